// Round 8
// baseline (206.902 us; speedup 1.0000x reference)
//
#include <hip/hip_runtime.h>

// Problem constants: B=8, L=1024, H=512, F=4
// out = gate * [x | alpha @ x],  gate = sigmoid([x|enc] @ W_gate)
// alpha = masked_softmax(max_f(Y_f Y_f^T)),  Y = relu(x @ W_proj)
//
// Round 20 = R19 (198.9us best) + softmax/attn FUSION (smattn_kernel):
// grid 256 = 8 b (XCD pin) x 32 i-tiles of 32 rows, 512 thr. Phase 1: each
// wave softmaxes 4 rows (coalesced float4 S reads, wave-wide shfl_xor
// reduces, same math as proven softmax kernel) and writes fp16 alpha into
// 64KB LDS in MFMA A-fragment layout (16 chunks [32][64], row&7 XOR swz).
// Phase 2 (one barrier, then barrier-free): enc tile = alpha(32x1024) @
// x(1024x512) with A-frags from LDS and B-frags read per-lane DIRECT from
// xT global (1MB/batch, L2-resident; ping-pong named reg arrays, rule #20).
// Kills: alpha buffer (16MB HBM write + ~64MB re-reads), attn staging, one
// dispatch. proj/score/gate/prep unchanged from R19.

typedef _Float16 half8 __attribute__((ext_vector_type(8)));
typedef _Float16 half4v __attribute__((ext_vector_type(4)));
typedef float floatx4 __attribute__((ext_vector_type(4)));

typedef const __attribute__((address_space(1))) void* gas_ptr;
typedef __attribute__((address_space(3))) void* las_ptr;

// ---- staging machinery: BK=64 rows (64 fp16/row), XOR-swizzle by row&7 ----

template<int NCH, int NT>
__device__ __forceinline__ void init_ptrs(const _Float16* src, int row0, int ld,
                                          const _Float16* gp[NCH]) {
  int t = threadIdx.x;
#pragma unroll
  for (int p = 0; p < NCH; ++p) {
    int c = p * NT + t;
    int row = c >> 3;
    int kg = c & 7;
    int gk = (kg ^ (row & 7)) << 3;
    gp[p] = src + (size_t)(row0 + row) * ld + gk;
  }
}

template<int NCH, int NT>
__device__ __forceinline__ void stage(const _Float16* const gp[NCH], _Float16* ldsbuf) {
  int t = threadIdx.x;
#pragma unroll
  for (int p = 0; p < NCH; ++p)
    __builtin_amdgcn_global_load_lds((gas_ptr)gp[p],
                                     (las_ptr)(ldsbuf + t * 8 + p * NT * 8), 16, 0, 0);
}

template<int NCH>
__device__ __forceinline__ void bump(const _Float16* gp[NCH], int d) {
#pragma unroll
  for (int p = 0; p < NCH; ++p) gp[p] += d;
}

__device__ __forceinline__ half8 frag_ld(const _Float16* lds, int row, int g) {
  return *(const half8*)(lds + row * 64 + ((g ^ (row & 7)) << 3));
}

// 4-wave (2x2) block: wave tile 64x64, per-lane acc 4x4
__device__ __forceinline__ void mfma_tile44(const _Float16* lds_a, const _Float16* lds_b,
                                            floatx4 acc[4][4], int wm, int wn,
                                            int l16, int quad) {
#pragma unroll
  for (int kf = 0; kf < 2; ++kf) {
    half8 af[4], bf[4];
#pragma unroll
    for (int i = 0; i < 4; ++i) af[i] = frag_ld(lds_a, wm * 64 + i * 16 + l16, kf * 4 + quad);
#pragma unroll
    for (int i = 0; i < 4; ++i) bf[i] = frag_ld(lds_b, wn * 64 + i * 16 + l16, kf * 4 + quad);
#pragma unroll
    for (int mi = 0; mi < 4; ++mi)
#pragma unroll
      for (int ni = 0; ni < 4; ++ni)
        acc[mi][ni] = __builtin_amdgcn_mfma_f32_16x16x32_f16(af[mi], bf[ni], acc[mi][ni], 0, 0, 0);
  }
}

#define ZERO_ACC44(acc)                                 \
  _Pragma("unroll") for (int mi = 0; mi < 4; ++mi)      \
  _Pragma("unroll") for (int ni = 0; ni < 4; ++ni)      \
  _Pragma("unroll") for (int r = 0; r < 4; ++r) acc[mi][ni][r] = 0.0f;

// wave tile 64x32, per-lane acc 4x2 (score)
__device__ __forceinline__ void mfma_tile42(const _Float16* la, const _Float16* lb,
                                            floatx4 acc[4][2], int wm, int wn,
                                            int l16, int quad) {
#pragma unroll
  for (int kf = 0; kf < 2; ++kf) {
    half8 af[4], bf[2];
#pragma unroll
    for (int i = 0; i < 4; ++i) af[i] = frag_ld(la, wm * 64 + i * 16 + l16, kf * 4 + quad);
#pragma unroll
    for (int i = 0; i < 2; ++i) bf[i] = frag_ld(lb, wn * 32 + i * 16 + l16, kf * 4 + quad);
#pragma unroll
    for (int mi = 0; mi < 4; ++mi)
#pragma unroll
      for (int ni = 0; ni < 2; ++ni)
        acc[mi][ni] = __builtin_amdgcn_mfma_f32_16x16x32_f16(af[mi], bf[ni], acc[mi][ni], 0, 0, 0);
  }
}

#define ZERO_ACC42(acc)                                 \
  _Pragma("unroll") for (int mi = 0; mi < 4; ++mi)      \
  _Pragma("unroll") for (int ni = 0; ni < 2; ++ni)      \
  _Pragma("unroll") for (int r = 0; r < 4; ++r) acc[mi][ni][r] = 0.0f;

// ---- merged pre-pass: ids [0,4096) = x_prep, [4096,6144) = w_prep ----

__global__ __launch_bounds__(256) void prep_kernel(const float* __restrict__ xin,
                                                   _Float16* __restrict__ x16,
                                                   _Float16* __restrict__ xT,
                                                   const float* __restrict__ Wp,
                                                   _Float16* __restrict__ WpT,
                                                   const float* __restrict__ Wg,
                                                   _Float16* __restrict__ WgT) {
  __shared__ float tile[32][33];
  int id = blockIdx.x;
  int tx = threadIdx.x & 31, ty = threadIdx.x >> 5;  // 32 x 8
  if (id < 4096) {
    const int R = 1024, C = 512;
    int b = id & 7, rest = id >> 3;
    int c0 = (rest & 15) * 32, r0 = (rest >> 4) * 32;
    size_t boff = (size_t)b * R * C;
    const float* in = xin + boff;
    _Float16* o16 = x16 + boff;
    _Float16* oT = xT + boff;
#pragma unroll
    for (int i = 0; i < 32; i += 8) {
      float v = in[(size_t)(r0 + ty + i) * C + c0 + tx];
      tile[ty + i][tx] = v;
      o16[(size_t)(r0 + ty + i) * C + c0 + tx] = (_Float16)v;
    }
    __syncthreads();
#pragma unroll
    for (int i = 0; i < 32; i += 8)
      oT[(size_t)(c0 + ty + i) * R + r0 + tx] = (_Float16)tile[tx][ty + i];
  } else {
    // z=0: Wp (512,2048) -> WpT' (2048,512) row-permuted (col k=h*4+f ->
    // row f*512+h, so proj's output col n = f*512+h). z=1: Wg -> WgT.
    int w = id - 4096;
    int bx = w & 63, by = (w >> 6) & 15, bz = w >> 10;
    const float* in; _Float16* out; int R, C, c0, r0;
    if (bz == 0) {
      in = Wp; out = WpT; R = 512; C = 2048;
      c0 = bx * 32; r0 = by * 32;
    } else {
      in = Wg; out = WgT; R = 1024; C = 1024;
      c0 = (bx & 31) * 32; r0 = (by * 2 + (bx >> 5)) * 32;
    }
#pragma unroll
    for (int i = 0; i < 32; i += 8)
      tile[ty + i][tx] = in[(size_t)(r0 + ty + i) * C + c0 + tx];
    __syncthreads();
#pragma unroll
    for (int i = 0; i < 32; i += 8) {
      int rr = c0 + ty + i;            // original column index of `in`
      int prow = (bz == 0) ? ((rr & 3) * 512 + (rr >> 2)) : rr;
      out[(size_t)prow * R + r0 + tx] = (_Float16)tile[tx][ty + i];
    }
  }
}

// ---- K1: y = relu(x @ W_proj + b_proj) -> y_t (B,F,L,H) fp16 ----
// 256 thr, 2x2 waves, 128x128 tile, dbuf BK=64, grid (64,16), 2 blk/CU.

__global__ __launch_bounds__(256) void proj_kernel(const _Float16* __restrict__ x16,
                                                   const _Float16* __restrict__ WpT,
                                                   const float* __restrict__ bp,
                                                   _Float16* __restrict__ y_t) {
  __shared__ __align__(16) _Float16 ldsA[2][128 * 64];
  __shared__ __align__(16) _Float16 ldsB[2][128 * 64];
  int i0 = blockIdx.x * 128, n0 = blockIdx.y * 128;
  int t = threadIdx.x, lane = t & 63, w = t >> 6;
  int wm = w >> 1, wn = w & 1, quad = lane >> 4, l16 = lane & 15;
  const _Float16* gpA[4]; const _Float16* gpB[4];
  init_ptrs<4, 256>(x16, i0, 512, gpA);
  init_ptrs<4, 256>(WpT, n0, 512, gpB);
  floatx4 acc[4][4];
  ZERO_ACC44(acc);
  stage<4, 256>(gpA, ldsA[0]); bump<4>(gpA, 64);
  stage<4, 256>(gpB, ldsB[0]); bump<4>(gpB, 64);
#pragma unroll 1
  for (int kt = 0; kt < 8; ++kt) {
    __syncthreads();
    if (kt < 7) {
      stage<4, 256>(gpA, ldsA[(kt + 1) & 1]); bump<4>(gpA, 64);
      stage<4, 256>(gpB, ldsB[(kt + 1) & 1]); bump<4>(gpB, 64);
    }
    mfma_tile44(ldsA[kt & 1], ldsB[kt & 1], acc, wm, wn, l16, quad);
  }
#pragma unroll
  for (int mi = 0; mi < 4; ++mi)
#pragma unroll
    for (int ni = 0; ni < 4; ++ni)
#pragma unroll
      for (int r = 0; r < 4; ++r) {
        int gr = i0 + wm * 64 + mi * 16 + quad * 4 + r;   // 0..8191
        int gc = n0 + wn * 64 + ni * 16 + l16;            // permuted col f*512+h
        int f = gc >> 9, h = gc & 511;
        float c = fmaxf(acc[mi][ni][r] + bp[h * 4 + f], 0.0f);
        int b = gr >> 10, l = gr & 1023;
        y_t[(((size_t)(b * 4 + f)) * 1024 + l) * 512 + h] = (_Float16)c;
      }
}

// ---- K2: S[b,i,j] = max_f sum_h Y_f[i,h] Y_f[j,h]; S symmetric ----
// 576 blocks (8 b x 72 upper-tri 128x64 tiles) x 256 thr; b = id & 7 XCD pin.

__global__ __launch_bounds__(256, 3) void score_kernel(const _Float16* __restrict__ y_t,
                                                       float* __restrict__ S) {
  __shared__ __align__(16) char smem[49152];
  _Float16* LA0 = (_Float16*)smem;              // 16 KB (128x64)
  _Float16* LA1 = (_Float16*)(smem + 16384);    // 16 KB
  _Float16* LB0 = (_Float16*)(smem + 32768);    // 8 KB (64x64)
  _Float16* LB1 = (_Float16*)(smem + 40960);    // 8 KB
  int id = blockIdx.x;
  int b = id & 7;
  int tt = id >> 3;            // 0..71 upper-tri half-tile index
  int ti = 0;
  while (tt >= 16 - 2 * ti) { tt -= 16 - 2 * ti; ++ti; }
  int jh = 2 * ti + tt;        // 2*ti .. 15
  int i0 = ti * 128, j0 = jh * 64;
  int t = threadIdx.x, lane = t & 63, w = t >> 6;
  int wm = w >> 1, wn = w & 1, quad = lane >> 4, l16 = lane & 15;
  const int PLANE = 1024 * 512;
  const _Float16* base = y_t + (size_t)b * 4 * PLANE;
  const _Float16* gpA[4]; const _Float16* gpB[2];
  init_ptrs<4, 256>(base, i0, 512, gpA);
  init_ptrs<2, 256>(base, j0, 512, gpB);
  floatx4 acc[4][2], smax[4][2];
  ZERO_ACC42(acc);
  stage<4, 256>(gpA, LA0); bump<4>(gpA, 64);
  stage<2, 256>(gpB, LB0); bump<2>(gpB, 64);
#pragma unroll 1
  for (int f = 0; f < 4; ++f) {
#pragma unroll 1
    for (int kt = 0; kt < 8; ++kt) {
      __syncthreads();
      if (f * 8 + kt < 31) {
        if (kt == 7) { bump<4>(gpA, PLANE - 512); bump<2>(gpB, PLANE - 512); }
        stage<4, 256>(gpA, ((kt + 1) & 1) ? LA1 : LA0); bump<4>(gpA, 64);
        stage<2, 256>(gpB, ((kt + 1) & 1) ? LB1 : LB0); bump<2>(gpB, 64);
      }
      mfma_tile42((kt & 1) ? LA1 : LA0, (kt & 1) ? LB1 : LB0, acc, wm, wn, l16, quad);
    }
    if (f == 0) {
#pragma unroll
      for (int mi = 0; mi < 4; ++mi)
#pragma unroll
        for (int ni = 0; ni < 2; ++ni) smax[mi][ni] = acc[mi][ni];
    } else {
#pragma unroll
      for (int mi = 0; mi < 4; ++mi)
#pragma unroll
        for (int ni = 0; ni < 2; ++ni)
#pragma unroll
          for (int r = 0; r < 4; ++r)
            smax[mi][ni][r] = fmaxf(smax[mi][ni][r], acc[mi][ni][r]);
    }
    ZERO_ACC42(acc);
  }
  float* Sb = S + (size_t)b * 1024 * 1024;
#pragma unroll
  for (int mi = 0; mi < 4; ++mi)
#pragma unroll
    for (int ni = 0; ni < 2; ++ni)
#pragma unroll
      for (int r = 0; r < 4; ++r) {
        int gi = i0 + wm * 64 + mi * 16 + quad * 4 + r;
        int gj = j0 + wn * 32 + ni * 16 + l16;
        Sb[(size_t)gi * 1024 + gj] = smax[mi][ni][r];
      }
  if (jh >= 2 * ti + 2) {
    __syncthreads();                 // staging buffers dead
    float* tl = (float*)smem;        // [128][65] fp32
#pragma unroll
    for (int mi = 0; mi < 4; ++mi)
#pragma unroll
      for (int ni = 0; ni < 2; ++ni)
#pragma unroll
        for (int r = 0; r < 4; ++r)
          tl[(wm * 64 + mi * 16 + quad * 4 + r) * 65 + (wn * 32 + ni * 16 + l16)] =
              smax[mi][ni][r];
    __syncthreads();
#pragma unroll 1
    for (int k = 0; k < 32; ++k) {
      int flat = k * 256 + t;        // 0..8191
      int rm = flat >> 7, cm = flat & 127;   // rm: mirror row 0..63, cm: col 0..127
      Sb[(size_t)(j0 + rm) * 1024 + (i0 + cm)] = tl[cm * 65 + rm];
    }
  }
}

// ---- K3+K4 fused: masked softmax rows + enc = alpha @ x ----
// 256 blocks (8 b XCD-pinned x 32 i-tiles of 32 rows) x 512 thr.
// Phase 1: wave w softmaxes rows 4w..4w+3; alpha -> LDS in A-frag layout
// (16 chunks [32][64], row&7 XOR swizzle). Phase 2 (barrier-free): GEMM
// 32x1024 @ 1024x512; A from LDS, B per-lane direct from xT (L2-resident).

__global__ __launch_bounds__(512) void smattn_kernel(const float* __restrict__ S,
                                                     const int* __restrict__ xmask,
                                                     const _Float16* __restrict__ xT,
                                                     _Float16* __restrict__ enc) {
  __shared__ __align__(16) _Float16 lal[16 * 2048];   // 64 KB alpha chunks
  __shared__ float lm[1024];                          // mask as float
  int id = blockIdx.x;
  int b = id & 7, it = id >> 3;        // XCD pin; i-tile 0..31
  int i0 = it * 32;
  int t = threadIdx.x, lane = t & 63, w = t >> 6;
  lm[t] = (float)xmask[b * 1024 + t];
  lm[t + 512] = (float)xmask[b * 1024 + t + 512];
  __syncthreads();
  const float* Sb = S + ((size_t)b * 1024 + i0) * 1024;
#pragma unroll 1
  for (int rr = 0; rr < 4; ++rr) {
    int r = w * 4 + rr;                // 0..31 local row
    int grow = i0 + r;                 // global row in batch
    float rmv = lm[grow];
    const float* sr = Sb + (size_t)r * 1024;
    float e[16], mk[16];
    float vmax = 0.0f;
#pragma unroll
    for (int q = 0; q < 4; ++q) {
      float4 sv = *(const float4*)(sr + q * 256 + lane * 4);
#pragma unroll
      for (int u = 0; u < 4; ++u) {
        int j = q * 256 + lane * 4 + u;
        float m = (rmv != 0.0f && lm[j] != 0.0f && j != grow) ? 1.0f : 0.0f;
        float v = m * ((const float*)&sv)[u];
        mk[q * 4 + u] = m;
        e[q * 4 + u] = v;
        vmax = fmaxf(vmax, v);
      }
    }
#pragma unroll
    for (int off = 32; off; off >>= 1) vmax = fmaxf(vmax, __shfl_xor(vmax, off));
    float E = 0.0f, E2 = 0.0f;
#pragma unroll
    for (int i = 0; i < 16; ++i) {
      e[i] = expf(e[i] - vmax);
      E += e[i];
      E2 += e[i] * mk[i];
    }
#pragma unroll
    for (int off = 32; off; off >>= 1) {
      E += __shfl_xor(E, off);
      E2 += __shfl_xor(E2, off);
    }
    float inv = 1.0f / (E2 + 1e-13f * E);
    // write 16 alpha halves: j = q*256 + lane*4 + u -> chunk kt=q*4+(lane>>4),
    // group jg=(lane>>1)&7, pos off8=(lane&1)*4 (+u). b64 writes, 8B aligned.
#pragma unroll
    for (int q = 0; q < 4; ++q) {
      int kt = q * 4 + (lane >> 4);
      int jg = (lane >> 1) & 7;
      int off8 = (lane & 1) * 4;
      half4v hv;
#pragma unroll
      for (int u = 0; u < 4; ++u) hv[u] = (_Float16)(e[q * 4 + u] * mk[q * 4 + u] * inv);
      *(half4v*)(&lal[kt * 2048 + r * 64 + ((jg ^ (r & 7)) << 3) + off8]) = hv;
    }
  }
  __syncthreads();
  // ---- GEMM phase: barrier-free. Wave w owns n-cols [64w, 64w+64). ----
  int quad = lane >> 4, l16 = lane & 15;
  const _Float16* Bb = xT + (size_t)b * 512 * 1024;
  floatx4 acc[2][4];
#pragma unroll
  for (int mi = 0; mi < 2; ++mi)
#pragma unroll
    for (int ni = 0; ni < 4; ++ni)
#pragma unroll
      for (int r = 0; r < 4; ++r) acc[mi][ni][r] = 0.0f;
  half8 bfA[8], bfB[8];   // [ni*2+kf], ping-pong (named arrays, no dyn index)
#define LOADB(KT, BF)                                                           \
  _Pragma("unroll") for (int ni = 0; ni < 4; ++ni)                              \
  _Pragma("unroll") for (int kf = 0; kf < 2; ++kf)                              \
    BF[ni * 2 + kf] = *(const half8*)(Bb + (size_t)(w * 64 + ni * 16 + l16) * 1024 + \
                                      (KT) * 64 + ((kf * 4 + quad) << 3));
#define KSTEP(KT, BF)                                                           \
  {                                                                             \
    const _Float16* Ah = &lal[(KT) * 2048];                                     \
    half8 af[2][2];                                                             \
    _Pragma("unroll") for (int mi = 0; mi < 2; ++mi)                            \
    _Pragma("unroll") for (int kf = 0; kf < 2; ++kf)                            \
      af[mi][kf] = frag_ld(Ah, mi * 16 + l16, kf * 4 + quad);                   \
    _Pragma("unroll") for (int mi = 0; mi < 2; ++mi)                            \
    _Pragma("unroll") for (int ni = 0; ni < 4; ++ni)                            \
    _Pragma("unroll") for (int kf = 0; kf < 2; ++kf)                            \
      acc[mi][ni] = __builtin_amdgcn_mfma_f32_16x16x32_f16(af[mi][kf],          \
          BF[ni * 2 + kf], acc[mi][ni], 0, 0, 0);                               \
  }
  LOADB(0, bfA);
#pragma unroll 1
  for (int kt = 0; kt < 16; kt += 2) {
    LOADB(kt + 1, bfB);
    KSTEP(kt, bfA);
    if (kt + 2 < 16) { LOADB(kt + 2, bfA); }
    KSTEP(kt + 1, bfB);
  }
#undef LOADB
#undef KSTEP
  _Float16* eb = enc + (size_t)b * 1024 * 512;
#pragma unroll
  for (int mi = 0; mi < 2; ++mi)
#pragma unroll
    for (int ni = 0; ni < 4; ++ni)
#pragma unroll
      for (int r = 0; r < 4; ++r) {
        int gr = i0 + mi * 16 + quad * 4 + r;
        int gc = w * 64 + ni * 16 + l16;
        eb[(size_t)gr * 512 + gc] = (_Float16)acc[mi][ni][r];
      }
}

// ---- K5: gate = sigmoid([x|enc] @ W_gate + b_gate); out = gate*[x16|enc] ----
// 256 thr, 2x2 waves, dbuf BK=64, grid (64,8), 2 blk/CU.

__global__ __launch_bounds__(256) void gate_kernel(const _Float16* __restrict__ x16,
                                                   const _Float16* __restrict__ enc,
                                                   const _Float16* __restrict__ WgT,
                                                   const float* __restrict__ bg,
                                                   float* __restrict__ out) {
  __shared__ __align__(16) _Float16 ldsA[2][128 * 64];
  __shared__ __align__(16) _Float16 ldsB[2][128 * 64];
  int i0 = blockIdx.x * 128, n0 = blockIdx.y * 128;
  int t = threadIdx.x, lane = t & 63, w = t >> 6;
  int wm = w >> 1, wn = w & 1, quad = lane >> 4, l16 = lane & 15;
  const _Float16* gpA[4]; const _Float16* gpA2[4]; const _Float16* gpB[4];
  init_ptrs<4, 256>(x16, i0, 512, gpA);
  init_ptrs<4, 256>(enc, i0, 512, gpA2);
  init_ptrs<4, 256>(WgT, n0, 1024, gpB);
  floatx4 acc[4][4];
  ZERO_ACC44(acc);
  stage<4, 256>(gpA, ldsA[0]); bump<4>(gpA, 64);
  stage<4, 256>(gpB, ldsB[0]); bump<4>(gpB, 64);
#pragma unroll 1
  for (int kt = 0; kt < 16; ++kt) {
    __syncthreads();
    if (kt < 15) {
      if (kt < 7) { stage<4, 256>(gpA,  ldsA[(kt + 1) & 1]); bump<4>(gpA, 64); }
      else        { stage<4, 256>(gpA2, ldsA[(kt + 1) & 1]); bump<4>(gpA2, 64); }
      stage<4, 256>(gpB, ldsB[(kt + 1) & 1]); bump<4>(gpB, 64);
    }
    mfma_tile44(ldsA[kt & 1], ldsB[kt & 1], acc, wm, wn, l16, quad);
  }
#pragma unroll
  for (int mi = 0; mi < 4; ++mi)
#pragma unroll
    for (int ni = 0; ni < 4; ++ni)
#pragma unroll
      for (int r = 0; r < 4; ++r) {
        int gr = i0 + wm * 64 + mi * 16 + quad * 4 + r;  // 0..8191
        int gc = n0 + wn * 64 + ni * 16 + l16;           // 0..1023
        float c = acc[mi][ni][r] + bg[gc];
        float g = 1.0f / (1.0f + expf(-c));
        float jv = (gc < 512) ? (float)x16[(size_t)gr * 512 + gc]
                              : (float)enc[(size_t)gr * 512 + (gc - 512)];
        out[(size_t)gr * 1024 + gc] = g * jv;
      }
}

// ---- launch ----

extern "C" void kernel_launch(void* const* d_in, const int* in_sizes, int n_in,
                              void* d_out, int out_size, void* d_ws, size_t ws_size,
                              hipStream_t stream) {
  const float* x  = (const float*)d_in[0];   // (8,1024,512)
  const int* xm   = (const int*)d_in[1];     // (8,1024)
  const float* Wp = (const float*)d_in[2];   // (512,2048)
  const float* bp = (const float*)d_in[3];   // (2048)
  const float* Wg = (const float*)d_in[4];   // (1024,1024)
  const float* bg = (const float*)d_in[5];   // (1024)
  float* out = (float*)d_out;

  char* ws = (char*)d_ws;
  const size_t MB = 1024 * 1024;
  _Float16* x16 = (_Float16*)(ws);            // 8 MB  (8192,512)
  _Float16* xT  = (_Float16*)(ws + 8 * MB);   // 8 MB  (8,512,1024)
  _Float16* WpT = (_Float16*)(ws + 16 * MB);  // 2 MB  (2048,512) row-permuted
  _Float16* WgT = (_Float16*)(ws + 18 * MB);  // 2 MB  (1024,1024)
  _Float16* y_t = (_Float16*)(ws + 20 * MB);  // 32 MB (8,4,1024,512)
  float*    S   = (float*)(ws + 52 * MB);     // 32 MB (8,1024,1024)  [end: 84 MB]
  // y_t is dead after score_kernel: alias enc onto it
  _Float16* enc   = (_Float16*)(ws + 36 * MB); // 8 MB  (8,1024,512)

  prep_kernel<<<6144, 256, 0, stream>>>(x, x16, xT, Wp, WpT, Wg, WgT);

  proj_kernel<<<dim3(64, 16), 256, 0, stream>>>(x16, WpT, bp, y_t);
  score_kernel<<<576, 256, 0, stream>>>(y_t, S);
  smattn_kernel<<<256, 512, 0, stream>>>(S, xm, xT, enc);
  gate_kernel<<<dim3(64, 8), 256, 0, stream>>>(x16, enc, WgT, bg, out);
}

// Round 9
// 196.772 us; speedup vs baseline: 1.0515x; 1.0515x over previous
//
#include <hip/hip_runtime.h>

// Problem constants: B=8, L=1024, H=512, F=4
// out = gate * [x | alpha @ x],  gate = sigmoid([x|enc] @ W_gate)
// alpha = masked_softmax(max_f(Y_f Y_f^T)),  Y = relu(x @ W_proj)
//
// Round 21 = R19 (198.9us, session best) + vectorized softmax loads.
// R20's softmax+attn fusion measured 44us (MfmaUtil 6.7%, Occ 17%, HBM 8%):
// grid=256 -> 1 blk/CU, latency-bound softmax phase had no co-resident
// block to overlap with (old 8192-block softmax had 32 queued blocks/CU).
// Fusion reverted. softmax_kernel now reads S as float4 + mask as int4
// (4x fewer mem instructions; it runs ~4TB/s issue-limited) and stores
// alpha as one 8B half4. Identical math (E/E2 renorm). All else = R19.

typedef _Float16 half8 __attribute__((ext_vector_type(8)));
typedef _Float16 half4v __attribute__((ext_vector_type(4)));
typedef float floatx4 __attribute__((ext_vector_type(4)));

typedef const __attribute__((address_space(1))) void* gas_ptr;
typedef __attribute__((address_space(3))) void* las_ptr;

// ---- staging machinery: BK=64 rows (64 fp16/row), XOR-swizzle by row&7 ----
// Chunk c covers row=c>>3, group kg=c&7, global col (kg^(row&7))*8; LDS dst =
// c*16 B (wave-uniform base + lane*16 contract of global_load_lds). Row
// stride 128 B = 32 banks -> rows never alias; swizzle makes frag reads clean.

template<int NCH, int NT>
__device__ __forceinline__ void init_ptrs(const _Float16* src, int row0, int ld,
                                          const _Float16* gp[NCH]) {
  int t = threadIdx.x;
#pragma unroll
  for (int p = 0; p < NCH; ++p) {
    int c = p * NT + t;
    int row = c >> 3;
    int kg = c & 7;
    int gk = (kg ^ (row & 7)) << 3;
    gp[p] = src + (size_t)(row0 + row) * ld + gk;
  }
}

template<int NCH, int NT>
__device__ __forceinline__ void stage(const _Float16* const gp[NCH], _Float16* ldsbuf) {
  int t = threadIdx.x;
#pragma unroll
  for (int p = 0; p < NCH; ++p)
    __builtin_amdgcn_global_load_lds((gas_ptr)gp[p],
                                     (las_ptr)(ldsbuf + t * 8 + p * NT * 8), 16, 0, 0);
}

template<int NCH>
__device__ __forceinline__ void bump(const _Float16* gp[NCH], int d) {
#pragma unroll
  for (int p = 0; p < NCH; ++p) gp[p] += d;
}

__device__ __forceinline__ half8 frag_ld(const _Float16* lds, int row, int g) {
  return *(const half8*)(lds + row * 64 + ((g ^ (row & 7)) << 3));
}

// 4-wave (2x2) block: wave tile 64x64, per-lane acc 4x4
__device__ __forceinline__ void mfma_tile44(const _Float16* lds_a, const _Float16* lds_b,
                                            floatx4 acc[4][4], int wm, int wn,
                                            int l16, int quad) {
#pragma unroll
  for (int kf = 0; kf < 2; ++kf) {
    half8 af[4], bf[4];
#pragma unroll
    for (int i = 0; i < 4; ++i) af[i] = frag_ld(lds_a, wm * 64 + i * 16 + l16, kf * 4 + quad);
#pragma unroll
    for (int i = 0; i < 4; ++i) bf[i] = frag_ld(lds_b, wn * 64 + i * 16 + l16, kf * 4 + quad);
#pragma unroll
    for (int mi = 0; mi < 4; ++mi)
#pragma unroll
      for (int ni = 0; ni < 4; ++ni)
        acc[mi][ni] = __builtin_amdgcn_mfma_f32_16x16x32_f16(af[mi], bf[ni], acc[mi][ni], 0, 0, 0);
  }
}

#define ZERO_ACC44(acc)                                 \
  _Pragma("unroll") for (int mi = 0; mi < 4; ++mi)      \
  _Pragma("unroll") for (int ni = 0; ni < 4; ++ni)      \
  _Pragma("unroll") for (int r = 0; r < 4; ++r) acc[mi][ni][r] = 0.0f;

// wave tile 64x32, per-lane acc 4x2 (score/attn)
__device__ __forceinline__ void mfma_tile42(const _Float16* la, const _Float16* lb,
                                            floatx4 acc[4][2], int wm, int wn,
                                            int l16, int quad) {
#pragma unroll
  for (int kf = 0; kf < 2; ++kf) {
    half8 af[4], bf[2];
#pragma unroll
    for (int i = 0; i < 4; ++i) af[i] = frag_ld(la, wm * 64 + i * 16 + l16, kf * 4 + quad);
#pragma unroll
    for (int i = 0; i < 2; ++i) bf[i] = frag_ld(lb, wn * 32 + i * 16 + l16, kf * 4 + quad);
#pragma unroll
    for (int mi = 0; mi < 4; ++mi)
#pragma unroll
      for (int ni = 0; ni < 2; ++ni)
        acc[mi][ni] = __builtin_amdgcn_mfma_f32_16x16x32_f16(af[mi], bf[ni], acc[mi][ni], 0, 0, 0);
  }
}

#define ZERO_ACC42(acc)                                 \
  _Pragma("unroll") for (int mi = 0; mi < 4; ++mi)      \
  _Pragma("unroll") for (int ni = 0; ni < 2; ++ni)      \
  _Pragma("unroll") for (int r = 0; r < 4; ++r) acc[mi][ni][r] = 0.0f;

// ---- merged pre-pass: ids [0,4096) = x_prep, [4096,6144) = w_prep ----

__global__ __launch_bounds__(256) void prep_kernel(const float* __restrict__ xin,
                                                   _Float16* __restrict__ x16,
                                                   _Float16* __restrict__ xT,
                                                   const float* __restrict__ Wp,
                                                   _Float16* __restrict__ WpT,
                                                   const float* __restrict__ Wg,
                                                   _Float16* __restrict__ WgT) {
  __shared__ float tile[32][33];
  int id = blockIdx.x;
  int tx = threadIdx.x & 31, ty = threadIdx.x >> 5;  // 32 x 8
  if (id < 4096) {
    const int R = 1024, C = 512;
    int b = id & 7, rest = id >> 3;
    int c0 = (rest & 15) * 32, r0 = (rest >> 4) * 32;
    size_t boff = (size_t)b * R * C;
    const float* in = xin + boff;
    _Float16* o16 = x16 + boff;
    _Float16* oT = xT + boff;
#pragma unroll
    for (int i = 0; i < 32; i += 8) {
      float v = in[(size_t)(r0 + ty + i) * C + c0 + tx];
      tile[ty + i][tx] = v;
      o16[(size_t)(r0 + ty + i) * C + c0 + tx] = (_Float16)v;
    }
    __syncthreads();
#pragma unroll
    for (int i = 0; i < 32; i += 8)
      oT[(size_t)(c0 + ty + i) * R + r0 + tx] = (_Float16)tile[tx][ty + i];
  } else {
    // z=0: Wp (512,2048) -> WpT' (2048,512) row-permuted (col k=h*4+f ->
    // row f*512+h, so proj's output col n = f*512+h). z=1: Wg -> WgT.
    int w = id - 4096;
    int bx = w & 63, by = (w >> 6) & 15, bz = w >> 10;
    const float* in; _Float16* out; int R, C, c0, r0;
    if (bz == 0) {
      in = Wp; out = WpT; R = 512; C = 2048;
      c0 = bx * 32; r0 = by * 32;
    } else {
      in = Wg; out = WgT; R = 1024; C = 1024;
      c0 = (bx & 31) * 32; r0 = (by * 2 + (bx >> 5)) * 32;
    }
#pragma unroll
    for (int i = 0; i < 32; i += 8)
      tile[ty + i][tx] = in[(size_t)(r0 + ty + i) * C + c0 + tx];
    __syncthreads();
#pragma unroll
    for (int i = 0; i < 32; i += 8) {
      int rr = c0 + ty + i;            // original column index of `in`
      int prow = (bz == 0) ? ((rr & 3) * 512 + (rr >> 2)) : rr;
      out[(size_t)prow * R + r0 + tx] = (_Float16)tile[tx][ty + i];
    }
  }
}

// ---- K1: y = relu(x @ W_proj + b_proj) -> y_t (B,F,L,H) fp16 ----
// 256 thr, 2x2 waves, 128x128 tile, dbuf BK=64, grid (64,16), 2 blk/CU.

__global__ __launch_bounds__(256) void proj_kernel(const _Float16* __restrict__ x16,
                                                   const _Float16* __restrict__ WpT,
                                                   const float* __restrict__ bp,
                                                   _Float16* __restrict__ y_t) {
  __shared__ __align__(16) _Float16 ldsA[2][128 * 64];
  __shared__ __align__(16) _Float16 ldsB[2][128 * 64];
  int i0 = blockIdx.x * 128, n0 = blockIdx.y * 128;
  int t = threadIdx.x, lane = t & 63, w = t >> 6;
  int wm = w >> 1, wn = w & 1, quad = lane >> 4, l16 = lane & 15;
  const _Float16* gpA[4]; const _Float16* gpB[4];
  init_ptrs<4, 256>(x16, i0, 512, gpA);
  init_ptrs<4, 256>(WpT, n0, 512, gpB);
  floatx4 acc[4][4];
  ZERO_ACC44(acc);
  stage<4, 256>(gpA, ldsA[0]); bump<4>(gpA, 64);
  stage<4, 256>(gpB, ldsB[0]); bump<4>(gpB, 64);
#pragma unroll 1
  for (int kt = 0; kt < 8; ++kt) {
    __syncthreads();
    if (kt < 7) {
      stage<4, 256>(gpA, ldsA[(kt + 1) & 1]); bump<4>(gpA, 64);
      stage<4, 256>(gpB, ldsB[(kt + 1) & 1]); bump<4>(gpB, 64);
    }
    mfma_tile44(ldsA[kt & 1], ldsB[kt & 1], acc, wm, wn, l16, quad);
  }
#pragma unroll
  for (int mi = 0; mi < 4; ++mi)
#pragma unroll
    for (int ni = 0; ni < 4; ++ni)
#pragma unroll
      for (int r = 0; r < 4; ++r) {
        int gr = i0 + wm * 64 + mi * 16 + quad * 4 + r;   // 0..8191
        int gc = n0 + wn * 64 + ni * 16 + l16;            // permuted col f*512+h
        int f = gc >> 9, h = gc & 511;
        float c = fmaxf(acc[mi][ni][r] + bp[h * 4 + f], 0.0f);
        int b = gr >> 10, l = gr & 1023;
        y_t[(((size_t)(b * 4 + f)) * 1024 + l) * 512 + h] = (_Float16)c;
      }
}

// ---- K2: S[b,i,j] = max_f sum_h Y_f[i,h] Y_f[j,h]; S symmetric ----
// 576 blocks (8 b x 72 upper-tri 128x64 tiles) x 256 thr; b = id & 7 XCD pin.
// 48KB LDS -> 3 blocks/CU. Diagonal covered by jh=2ti/2ti+1 direct;
// jh>=2ti+2 mirrored via [128][65] fp32 LDS transpose (conflict-free).

__global__ __launch_bounds__(256, 3) void score_kernel(const _Float16* __restrict__ y_t,
                                                       float* __restrict__ S) {
  __shared__ __align__(16) char smem[49152];
  _Float16* LA0 = (_Float16*)smem;              // 16 KB (128x64)
  _Float16* LA1 = (_Float16*)(smem + 16384);    // 16 KB
  _Float16* LB0 = (_Float16*)(smem + 32768);    // 8 KB (64x64)
  _Float16* LB1 = (_Float16*)(smem + 40960);    // 8 KB
  int id = blockIdx.x;
  int b = id & 7;
  int tt = id >> 3;            // 0..71 upper-tri half-tile index
  int ti = 0;
  while (tt >= 16 - 2 * ti) { tt -= 16 - 2 * ti; ++ti; }
  int jh = 2 * ti + tt;        // 2*ti .. 15
  int i0 = ti * 128, j0 = jh * 64;
  int t = threadIdx.x, lane = t & 63, w = t >> 6;
  int wm = w >> 1, wn = w & 1, quad = lane >> 4, l16 = lane & 15;
  const int PLANE = 1024 * 512;
  const _Float16* base = y_t + (size_t)b * 4 * PLANE;
  const _Float16* gpA[4]; const _Float16* gpB[2];
  init_ptrs<4, 256>(base, i0, 512, gpA);
  init_ptrs<2, 256>(base, j0, 512, gpB);
  floatx4 acc[4][2], smax[4][2];
  ZERO_ACC42(acc);
  stage<4, 256>(gpA, LA0); bump<4>(gpA, 64);
  stage<2, 256>(gpB, LB0); bump<2>(gpB, 64);
#pragma unroll 1
  for (int f = 0; f < 4; ++f) {
#pragma unroll 1
    for (int kt = 0; kt < 8; ++kt) {
      __syncthreads();
      if (f * 8 + kt < 31) {
        if (kt == 7) { bump<4>(gpA, PLANE - 512); bump<2>(gpB, PLANE - 512); }
        stage<4, 256>(gpA, ((kt + 1) & 1) ? LA1 : LA0); bump<4>(gpA, 64);
        stage<2, 256>(gpB, ((kt + 1) & 1) ? LB1 : LB0); bump<2>(gpB, 64);
      }
      mfma_tile42((kt & 1) ? LA1 : LA0, (kt & 1) ? LB1 : LB0, acc, wm, wn, l16, quad);
    }
    if (f == 0) {
#pragma unroll
      for (int mi = 0; mi < 4; ++mi)
#pragma unroll
        for (int ni = 0; ni < 2; ++ni) smax[mi][ni] = acc[mi][ni];
    } else {
#pragma unroll
      for (int mi = 0; mi < 4; ++mi)
#pragma unroll
        for (int ni = 0; ni < 2; ++ni)
#pragma unroll
          for (int r = 0; r < 4; ++r)
            smax[mi][ni][r] = fmaxf(smax[mi][ni][r], acc[mi][ni][r]);
    }
    ZERO_ACC42(acc);
  }
  float* Sb = S + (size_t)b * 1024 * 1024;
#pragma unroll
  for (int mi = 0; mi < 4; ++mi)
#pragma unroll
    for (int ni = 0; ni < 2; ++ni)
#pragma unroll
      for (int r = 0; r < 4; ++r) {
        int gi = i0 + wm * 64 + mi * 16 + quad * 4 + r;
        int gj = j0 + wn * 32 + ni * 16 + l16;
        Sb[(size_t)gi * 1024 + gj] = smax[mi][ni][r];
      }
  if (jh >= 2 * ti + 2) {
    __syncthreads();                 // staging buffers dead
    float* tl = (float*)smem;        // [128][65] fp32
#pragma unroll
    for (int mi = 0; mi < 4; ++mi)
#pragma unroll
      for (int ni = 0; ni < 2; ++ni)
#pragma unroll
        for (int r = 0; r < 4; ++r)
          tl[(wm * 64 + mi * 16 + quad * 4 + r) * 65 + (wn * 32 + ni * 16 + l16)] =
              smax[mi][ni][r];
    __syncthreads();
#pragma unroll 1
    for (int k = 0; k < 32; ++k) {
      int flat = k * 256 + t;        // 0..8191
      int rm = flat >> 7, cm = flat & 127;   // rm: mirror row 0..63, cm: col 0..127
      Sb[(size_t)(j0 + rm) * 1024 + (i0 + cm)] = tl[cm * 65 + rm];
    }
  }
}

// ---- K3: allennlp masked softmax per row -> alpha fp16 ----
// 8192 blocks x 256 thr; thread t owns elements [4t, 4t+4): float4 S read,
// int4 mask read, half4 alpha write (4x fewer memory instructions).

__global__ __launch_bounds__(256) void softmax_kernel(const float* __restrict__ S,
                                                      const int* __restrict__ xmask,
                                                      _Float16* __restrict__ alpha) {
  __shared__ float red[16];
  int row = blockIdx.x;               // 0..8191
  int b = row >> 10, l = row & 1023;
  const float* sr = S + (size_t)row * 1024;
  const int* mr = xmask + b * 1024;
  int t = threadIdx.x, lane = t & 63, wid = t >> 6;
  int rm = mr[l];
  float4 sv = *(const float4*)(sr + t * 4);
  int4 mv = *(const int4*)(mr + t * 4);
  float v[4], mm[4];
  float vmax = 0.0f;
#pragma unroll
  for (int u = 0; u < 4; ++u) {
    int j = t * 4 + u;
    int mu = ((const int*)&mv)[u];
    int m = (rm && mu && (j != l)) ? 1 : 0;
    mm[u] = (float)m;
    v[u] = m ? ((const float*)&sv)[u] : 0.0f;
    vmax = fmaxf(vmax, v[u]);
  }
  for (int off = 32; off; off >>= 1) vmax = fmaxf(vmax, __shfl_down(vmax, off));
  if (lane == 0) red[wid] = vmax;
  __syncthreads();
  if (t == 0) red[8] = fmaxf(fmaxf(red[0], red[1]), fmaxf(red[2], red[3]));
  __syncthreads();
  vmax = red[8];
  float e[4], E = 0.0f, E2 = 0.0f;
#pragma unroll
  for (int u = 0; u < 4; ++u) {
    e[u] = expf(v[u] - vmax);
    E += e[u];
    E2 += e[u] * mm[u];
  }
  for (int off = 32; off; off >>= 1) {
    E += __shfl_down(E, off);
    E2 += __shfl_down(E2, off);
  }
  if (lane == 0) { red[wid] = E; red[4 + wid] = E2; }
  __syncthreads();
  if (t == 0) {
    red[9] = red[0] + red[1] + red[2] + red[3];
    red[10] = red[4] + red[5] + red[6] + red[7];
  }
  __syncthreads();
  E = red[9]; E2 = red[10];
  float inv = 1.0f / (E2 + 1e-13f * E);
  half4v hv;
#pragma unroll
  for (int u = 0; u < 4; ++u) hv[u] = (_Float16)(e[u] * mm[u] * inv);
  *(half4v*)(alpha + (size_t)row * 1024 + t * 4) = hv;
}

// ---- K4: enc[b] = alpha[b] @ x[b]  (xT (B,H,L) as B-operand) ----
// 512 blocks x 256 thr: 64-row i-tiles x 4 n-tiles x 8 b; b = id & 7 XCD pin.

__global__ __launch_bounds__(256) void attn_kernel(const _Float16* __restrict__ alpha,
                                                   const _Float16* __restrict__ xT,
                                                   _Float16* __restrict__ enc) {
  __shared__ __align__(16) _Float16 ldsA[2][64 * 64];
  __shared__ __align__(16) _Float16 ldsB[2][128 * 64];
  int id = blockIdx.x;
  int b = id & 7;
  int r2 = id >> 3;                 // 0..63
  int i0 = (r2 >> 2) * 64;
  int n0 = (r2 & 3) * 128;
  const _Float16* A = alpha + (size_t)b * 1024 * 1024;
  const _Float16* Bm = xT + (size_t)b * 512 * 1024;
  int t = threadIdx.x, lane = t & 63, wn = t >> 6;   // wave grid 1x4
  int quad = lane >> 4, l16 = lane & 15;
  const _Float16* gpA[2]; const _Float16* gpB[4];
  init_ptrs<2, 256>(A, i0, 1024, gpA);
  init_ptrs<4, 256>(Bm, n0, 1024, gpB);
  floatx4 acc[4][2];
  ZERO_ACC42(acc);
  stage<2, 256>(gpA, ldsA[0]); bump<2>(gpA, 64);
  stage<4, 256>(gpB, ldsB[0]); bump<4>(gpB, 64);
#pragma unroll 1
  for (int kt = 0; kt < 16; ++kt) {
    __syncthreads();
    if (kt < 15) {
      stage<2, 256>(gpA, ldsA[(kt + 1) & 1]); bump<2>(gpA, 64);
      stage<4, 256>(gpB, ldsB[(kt + 1) & 1]); bump<4>(gpB, 64);
    }
    const _Float16* la = ldsA[kt & 1];
    const _Float16* lb = ldsB[kt & 1];
#pragma unroll
    for (int kf = 0; kf < 2; ++kf) {
      half8 af[4], bf[2];
#pragma unroll
      for (int i = 0; i < 4; ++i) af[i] = frag_ld(la, i * 16 + l16, kf * 4 + quad);
#pragma unroll
      for (int i = 0; i < 2; ++i) bf[i] = frag_ld(lb, wn * 32 + i * 16 + l16, kf * 4 + quad);
#pragma unroll
      for (int mi = 0; mi < 4; ++mi)
#pragma unroll
        for (int ni = 0; ni < 2; ++ni)
          acc[mi][ni] = __builtin_amdgcn_mfma_f32_16x16x32_f16(af[mi], bf[ni], acc[mi][ni], 0, 0, 0);
    }
  }
  _Float16* eb = enc + (size_t)b * 1024 * 512;
#pragma unroll
  for (int mi = 0; mi < 4; ++mi)
#pragma unroll
    for (int ni = 0; ni < 2; ++ni)
#pragma unroll
      for (int r = 0; r < 4; ++r) {
        int gr = i0 + mi * 16 + quad * 4 + r;
        int gc = n0 + wn * 32 + ni * 16 + l16;
        eb[(size_t)gr * 512 + gc] = (_Float16)acc[mi][ni][r];
      }
}

// ---- K5: gate = sigmoid([x|enc] @ W_gate + b_gate); out = gate*[x16|enc] ----
// 256 thr, 2x2 waves, dbuf BK=64, grid (64,8), 2 blk/CU.

__global__ __launch_bounds__(256) void gate_kernel(const _Float16* __restrict__ x16,
                                                   const _Float16* __restrict__ enc,
                                                   const _Float16* __restrict__ WgT,
                                                   const float* __restrict__ bg,
                                                   float* __restrict__ out) {
  __shared__ __align__(16) _Float16 ldsA[2][128 * 64];
  __shared__ __align__(16) _Float16 ldsB[2][128 * 64];
  int i0 = blockIdx.x * 128, n0 = blockIdx.y * 128;
  int t = threadIdx.x, lane = t & 63, w = t >> 6;
  int wm = w >> 1, wn = w & 1, quad = lane >> 4, l16 = lane & 15;
  const _Float16* gpA[4]; const _Float16* gpA2[4]; const _Float16* gpB[4];
  init_ptrs<4, 256>(x16, i0, 512, gpA);
  init_ptrs<4, 256>(enc, i0, 512, gpA2);
  init_ptrs<4, 256>(WgT, n0, 1024, gpB);
  floatx4 acc[4][4];
  ZERO_ACC44(acc);
  stage<4, 256>(gpA, ldsA[0]); bump<4>(gpA, 64);
  stage<4, 256>(gpB, ldsB[0]); bump<4>(gpB, 64);
#pragma unroll 1
  for (int kt = 0; kt < 16; ++kt) {
    __syncthreads();
    if (kt < 15) {
      if (kt < 7) { stage<4, 256>(gpA,  ldsA[(kt + 1) & 1]); bump<4>(gpA, 64); }
      else        { stage<4, 256>(gpA2, ldsA[(kt + 1) & 1]); bump<4>(gpA2, 64); }
      stage<4, 256>(gpB, ldsB[(kt + 1) & 1]); bump<4>(gpB, 64);
    }
    mfma_tile44(ldsA[kt & 1], ldsB[kt & 1], acc, wm, wn, l16, quad);
  }
#pragma unroll
  for (int mi = 0; mi < 4; ++mi)
#pragma unroll
    for (int ni = 0; ni < 4; ++ni)
#pragma unroll
      for (int r = 0; r < 4; ++r) {
        int gr = i0 + wm * 64 + mi * 16 + quad * 4 + r;  // 0..8191
        int gc = n0 + wn * 64 + ni * 16 + l16;           // 0..1023
        float c = acc[mi][ni][r] + bg[gc];
        float g = 1.0f / (1.0f + expf(-c));
        float jv = (gc < 512) ? (float)x16[(size_t)gr * 512 + gc]
                              : (float)enc[(size_t)gr * 512 + (gc - 512)];
        out[(size_t)gr * 1024 + gc] = g * jv;
      }
}

// ---- launch ----

extern "C" void kernel_launch(void* const* d_in, const int* in_sizes, int n_in,
                              void* d_out, int out_size, void* d_ws, size_t ws_size,
                              hipStream_t stream) {
  const float* x  = (const float*)d_in[0];   // (8,1024,512)
  const int* xm   = (const int*)d_in[1];     // (8,1024)
  const float* Wp = (const float*)d_in[2];   // (512,2048)
  const float* bp = (const float*)d_in[3];   // (2048)
  const float* Wg = (const float*)d_in[4];   // (1024,1024)
  const float* bg = (const float*)d_in[5];   // (1024)
  float* out = (float*)d_out;

  char* ws = (char*)d_ws;
  const size_t MB = 1024 * 1024;
  _Float16* x16 = (_Float16*)(ws);            // 8 MB  (8192,512)
  _Float16* xT  = (_Float16*)(ws + 8 * MB);   // 8 MB  (8,512,1024)
  _Float16* WpT = (_Float16*)(ws + 16 * MB);  // 2 MB  (2048,512) row-permuted
  _Float16* WgT = (_Float16*)(ws + 18 * MB);  // 2 MB  (1024,1024)
  _Float16* y_t = (_Float16*)(ws + 20 * MB);  // 32 MB (8,4,1024,512)
  float*    S   = (float*)(ws + 52 * MB);     // 32 MB (8,1024,1024)  [end: 84 MB]
  // y_t is dead after score_kernel: alias alpha/enc onto it
  _Float16* alpha = (_Float16*)(ws + 20 * MB); // 16 MB (8,1024,1024)
  _Float16* enc   = (_Float16*)(ws + 36 * MB); // 8 MB  (8,1024,512)

  prep_kernel<<<6144, 256, 0, stream>>>(x, x16, xT, Wp, WpT, Wg, WgT);

  proj_kernel<<<dim3(64, 16), 256, 0, stream>>>(x16, WpT, bp, y_t);
  score_kernel<<<576, 256, 0, stream>>>(y_t, S);
  softmax_kernel<<<8192, 256, 0, stream>>>(S, xm, alpha);
  attn_kernel<<<512, 256, 0, stream>>>(alpha, xT, enc);
  gate_kernel<<<dim3(64, 8), 256, 0, stream>>>(x16, enc, WgT, bg, out);
}

// Round 11
// 195.550 us; speedup vs baseline: 1.0581x; 1.0062x over previous
//
#include <hip/hip_runtime.h>

// Problem constants: B=8, L=1024, H=512, F=4
// out = gate * [x | alpha @ x],  gate = sigmoid([x|enc] @ W_gate)
// alpha = masked_softmax(max_f(Y_f Y_f^T)),  Y = relu(x @ W_proj)
//
// Round 23 = exact revert to R21 (196.8us, session best). R22's fp16-S
// failed absmax 0.09375 > 0.088 (quantization margin too thin); fp32 S
// restored. Session ledger: R13 rebalance +3us; R14 XCD pin neutral;
// R15-R18 deep pipelines all slower (coarse counted-vmcnt AND faithful
// 8-phase lose to 2-phase + 2blk/CU at K=512-2048/block); R20 softmax+attn
// fusion slower (latency exposure at 1 blk/CU); R21 vectorized softmax
// +2us; R22 fp16 S fails accuracy. This structure is the measured optimum
// of everything tried: 2-phase dbuf BK=64 GEMMs at 2 blk/CU, upper-tri
// score with LDS-transpose mirror, vectorized 8192-block softmax, merged
// prep, XCD-pinned score/attn.

typedef _Float16 half8 __attribute__((ext_vector_type(8)));
typedef _Float16 half4v __attribute__((ext_vector_type(4)));
typedef float floatx4 __attribute__((ext_vector_type(4)));

typedef const __attribute__((address_space(1))) void* gas_ptr;
typedef __attribute__((address_space(3))) void* las_ptr;

// ---- staging machinery: BK=64 rows (64 fp16/row), XOR-swizzle by row&7 ----
// Chunk c covers row=c>>3, group kg=c&7, global col (kg^(row&7))*8; LDS dst =
// c*16 B (wave-uniform base + lane*16 contract of global_load_lds). Row
// stride 128 B = 32 banks -> rows never alias; swizzle makes frag reads clean.

template<int NCH, int NT>
__device__ __forceinline__ void init_ptrs(const _Float16* src, int row0, int ld,
                                          const _Float16* gp[NCH]) {
  int t = threadIdx.x;
#pragma unroll
  for (int p = 0; p < NCH; ++p) {
    int c = p * NT + t;
    int row = c >> 3;
    int kg = c & 7;
    int gk = (kg ^ (row & 7)) << 3;
    gp[p] = src + (size_t)(row0 + row) * ld + gk;
  }
}

template<int NCH, int NT>
__device__ __forceinline__ void stage(const _Float16* const gp[NCH], _Float16* ldsbuf) {
  int t = threadIdx.x;
#pragma unroll
  for (int p = 0; p < NCH; ++p)
    __builtin_amdgcn_global_load_lds((gas_ptr)gp[p],
                                     (las_ptr)(ldsbuf + t * 8 + p * NT * 8), 16, 0, 0);
}

template<int NCH>
__device__ __forceinline__ void bump(const _Float16* gp[NCH], int d) {
#pragma unroll
  for (int p = 0; p < NCH; ++p) gp[p] += d;
}

__device__ __forceinline__ half8 frag_ld(const _Float16* lds, int row, int g) {
  return *(const half8*)(lds + row * 64 + ((g ^ (row & 7)) << 3));
}

// 4-wave (2x2) block: wave tile 64x64, per-lane acc 4x4
__device__ __forceinline__ void mfma_tile44(const _Float16* lds_a, const _Float16* lds_b,
                                            floatx4 acc[4][4], int wm, int wn,
                                            int l16, int quad) {
#pragma unroll
  for (int kf = 0; kf < 2; ++kf) {
    half8 af[4], bf[4];
#pragma unroll
    for (int i = 0; i < 4; ++i) af[i] = frag_ld(lds_a, wm * 64 + i * 16 + l16, kf * 4 + quad);
#pragma unroll
    for (int i = 0; i < 4; ++i) bf[i] = frag_ld(lds_b, wn * 64 + i * 16 + l16, kf * 4 + quad);
#pragma unroll
    for (int mi = 0; mi < 4; ++mi)
#pragma unroll
      for (int ni = 0; ni < 4; ++ni)
        acc[mi][ni] = __builtin_amdgcn_mfma_f32_16x16x32_f16(af[mi], bf[ni], acc[mi][ni], 0, 0, 0);
  }
}

#define ZERO_ACC44(acc)                                 \
  _Pragma("unroll") for (int mi = 0; mi < 4; ++mi)      \
  _Pragma("unroll") for (int ni = 0; ni < 4; ++ni)      \
  _Pragma("unroll") for (int r = 0; r < 4; ++r) acc[mi][ni][r] = 0.0f;

// wave tile 64x32, per-lane acc 4x2 (score/attn)
__device__ __forceinline__ void mfma_tile42(const _Float16* la, const _Float16* lb,
                                            floatx4 acc[4][2], int wm, int wn,
                                            int l16, int quad) {
#pragma unroll
  for (int kf = 0; kf < 2; ++kf) {
    half8 af[4], bf[2];
#pragma unroll
    for (int i = 0; i < 4; ++i) af[i] = frag_ld(la, wm * 64 + i * 16 + l16, kf * 4 + quad);
#pragma unroll
    for (int i = 0; i < 2; ++i) bf[i] = frag_ld(lb, wn * 32 + i * 16 + l16, kf * 4 + quad);
#pragma unroll
    for (int mi = 0; mi < 4; ++mi)
#pragma unroll
      for (int ni = 0; ni < 2; ++ni)
        acc[mi][ni] = __builtin_amdgcn_mfma_f32_16x16x32_f16(af[mi], bf[ni], acc[mi][ni], 0, 0, 0);
  }
}

#define ZERO_ACC42(acc)                                 \
  _Pragma("unroll") for (int mi = 0; mi < 4; ++mi)      \
  _Pragma("unroll") for (int ni = 0; ni < 2; ++ni)      \
  _Pragma("unroll") for (int r = 0; r < 4; ++r) acc[mi][ni][r] = 0.0f;

// ---- merged pre-pass: ids [0,4096) = x_prep, [4096,6144) = w_prep ----

__global__ __launch_bounds__(256) void prep_kernel(const float* __restrict__ xin,
                                                   _Float16* __restrict__ x16,
                                                   _Float16* __restrict__ xT,
                                                   const float* __restrict__ Wp,
                                                   _Float16* __restrict__ WpT,
                                                   const float* __restrict__ Wg,
                                                   _Float16* __restrict__ WgT) {
  __shared__ float tile[32][33];
  int id = blockIdx.x;
  int tx = threadIdx.x & 31, ty = threadIdx.x >> 5;  // 32 x 8
  if (id < 4096) {
    const int R = 1024, C = 512;
    int b = id & 7, rest = id >> 3;
    int c0 = (rest & 15) * 32, r0 = (rest >> 4) * 32;
    size_t boff = (size_t)b * R * C;
    const float* in = xin + boff;
    _Float16* o16 = x16 + boff;
    _Float16* oT = xT + boff;
#pragma unroll
    for (int i = 0; i < 32; i += 8) {
      float v = in[(size_t)(r0 + ty + i) * C + c0 + tx];
      tile[ty + i][tx] = v;
      o16[(size_t)(r0 + ty + i) * C + c0 + tx] = (_Float16)v;
    }
    __syncthreads();
#pragma unroll
    for (int i = 0; i < 32; i += 8)
      oT[(size_t)(c0 + ty + i) * R + r0 + tx] = (_Float16)tile[tx][ty + i];
  } else {
    // z=0: Wp (512,2048) -> WpT' (2048,512) row-permuted (col k=h*4+f ->
    // row f*512+h, so proj's output col n = f*512+h). z=1: Wg -> WgT.
    int w = id - 4096;
    int bx = w & 63, by = (w >> 6) & 15, bz = w >> 10;
    const float* in; _Float16* out; int R, C, c0, r0;
    if (bz == 0) {
      in = Wp; out = WpT; R = 512; C = 2048;
      c0 = bx * 32; r0 = by * 32;
    } else {
      in = Wg; out = WgT; R = 1024; C = 1024;
      c0 = (bx & 31) * 32; r0 = (by * 2 + (bx >> 5)) * 32;
    }
#pragma unroll
    for (int i = 0; i < 32; i += 8)
      tile[ty + i][tx] = in[(size_t)(r0 + ty + i) * C + c0 + tx];
    __syncthreads();
#pragma unroll
    for (int i = 0; i < 32; i += 8) {
      int rr = c0 + ty + i;            // original column index of `in`
      int prow = (bz == 0) ? ((rr & 3) * 512 + (rr >> 2)) : rr;
      out[(size_t)prow * R + r0 + tx] = (_Float16)tile[tx][ty + i];
    }
  }
}

// ---- K1: y = relu(x @ W_proj + b_proj) -> y_t (B,F,L,H) fp16 ----
// 256 thr, 2x2 waves, 128x128 tile, dbuf BK=64, grid (64,16), 2 blk/CU.

__global__ __launch_bounds__(256) void proj_kernel(const _Float16* __restrict__ x16,
                                                   const _Float16* __restrict__ WpT,
                                                   const float* __restrict__ bp,
                                                   _Float16* __restrict__ y_t) {
  __shared__ __align__(16) _Float16 ldsA[2][128 * 64];
  __shared__ __align__(16) _Float16 ldsB[2][128 * 64];
  int i0 = blockIdx.x * 128, n0 = blockIdx.y * 128;
  int t = threadIdx.x, lane = t & 63, w = t >> 6;
  int wm = w >> 1, wn = w & 1, quad = lane >> 4, l16 = lane & 15;
  const _Float16* gpA[4]; const _Float16* gpB[4];
  init_ptrs<4, 256>(x16, i0, 512, gpA);
  init_ptrs<4, 256>(WpT, n0, 512, gpB);
  floatx4 acc[4][4];
  ZERO_ACC44(acc);
  stage<4, 256>(gpA, ldsA[0]); bump<4>(gpA, 64);
  stage<4, 256>(gpB, ldsB[0]); bump<4>(gpB, 64);
#pragma unroll 1
  for (int kt = 0; kt < 8; ++kt) {
    __syncthreads();
    if (kt < 7) {
      stage<4, 256>(gpA, ldsA[(kt + 1) & 1]); bump<4>(gpA, 64);
      stage<4, 256>(gpB, ldsB[(kt + 1) & 1]); bump<4>(gpB, 64);
    }
    mfma_tile44(ldsA[kt & 1], ldsB[kt & 1], acc, wm, wn, l16, quad);
  }
#pragma unroll
  for (int mi = 0; mi < 4; ++mi)
#pragma unroll
    for (int ni = 0; ni < 4; ++ni)
#pragma unroll
      for (int r = 0; r < 4; ++r) {
        int gr = i0 + wm * 64 + mi * 16 + quad * 4 + r;   // 0..8191
        int gc = n0 + wn * 64 + ni * 16 + l16;            // permuted col f*512+h
        int f = gc >> 9, h = gc & 511;
        float c = fmaxf(acc[mi][ni][r] + bp[h * 4 + f], 0.0f);
        int b = gr >> 10, l = gr & 1023;
        y_t[(((size_t)(b * 4 + f)) * 1024 + l) * 512 + h] = (_Float16)c;
      }
}

// ---- K2: S[b,i,j] = max_f sum_h Y_f[i,h] Y_f[j,h]; S symmetric ----
// 576 blocks (8 b x 72 upper-tri 128x64 tiles) x 256 thr; b = id & 7 XCD pin.
// 48KB LDS -> 3 blocks/CU. Diagonal covered by jh=2ti/2ti+1 direct;
// jh>=2ti+2 mirrored via [128][65] fp32 LDS transpose (conflict-free).

__global__ __launch_bounds__(256, 3) void score_kernel(const _Float16* __restrict__ y_t,
                                                       float* __restrict__ S) {
  __shared__ __align__(16) char smem[49152];
  _Float16* LA0 = (_Float16*)smem;              // 16 KB (128x64)
  _Float16* LA1 = (_Float16*)(smem + 16384);    // 16 KB
  _Float16* LB0 = (_Float16*)(smem + 32768);    // 8 KB (64x64)
  _Float16* LB1 = (_Float16*)(smem + 40960);    // 8 KB
  int id = blockIdx.x;
  int b = id & 7;
  int tt = id >> 3;            // 0..71 upper-tri half-tile index
  int ti = 0;
  while (tt >= 16 - 2 * ti) { tt -= 16 - 2 * ti; ++ti; }
  int jh = 2 * ti + tt;        // 2*ti .. 15
  int i0 = ti * 128, j0 = jh * 64;
  int t = threadIdx.x, lane = t & 63, w = t >> 6;
  int wm = w >> 1, wn = w & 1, quad = lane >> 4, l16 = lane & 15;
  const int PLANE = 1024 * 512;
  const _Float16* base = y_t + (size_t)b * 4 * PLANE;
  const _Float16* gpA[4]; const _Float16* gpB[2];
  init_ptrs<4, 256>(base, i0, 512, gpA);
  init_ptrs<2, 256>(base, j0, 512, gpB);
  floatx4 acc[4][2], smax[4][2];
  ZERO_ACC42(acc);
  stage<4, 256>(gpA, LA0); bump<4>(gpA, 64);
  stage<2, 256>(gpB, LB0); bump<2>(gpB, 64);
#pragma unroll 1
  for (int f = 0; f < 4; ++f) {
#pragma unroll 1
    for (int kt = 0; kt < 8; ++kt) {
      __syncthreads();
      if (f * 8 + kt < 31) {
        if (kt == 7) { bump<4>(gpA, PLANE - 512); bump<2>(gpB, PLANE - 512); }
        stage<4, 256>(gpA, ((kt + 1) & 1) ? LA1 : LA0); bump<4>(gpA, 64);
        stage<2, 256>(gpB, ((kt + 1) & 1) ? LB1 : LB0); bump<2>(gpB, 64);
      }
      mfma_tile42((kt & 1) ? LA1 : LA0, (kt & 1) ? LB1 : LB0, acc, wm, wn, l16, quad);
    }
    if (f == 0) {
#pragma unroll
      for (int mi = 0; mi < 4; ++mi)
#pragma unroll
        for (int ni = 0; ni < 2; ++ni) smax[mi][ni] = acc[mi][ni];
    } else {
#pragma unroll
      for (int mi = 0; mi < 4; ++mi)
#pragma unroll
        for (int ni = 0; ni < 2; ++ni)
#pragma unroll
          for (int r = 0; r < 4; ++r)
            smax[mi][ni][r] = fmaxf(smax[mi][ni][r], acc[mi][ni][r]);
    }
    ZERO_ACC42(acc);
  }
  float* Sb = S + (size_t)b * 1024 * 1024;
#pragma unroll
  for (int mi = 0; mi < 4; ++mi)
#pragma unroll
    for (int ni = 0; ni < 2; ++ni)
#pragma unroll
      for (int r = 0; r < 4; ++r) {
        int gi = i0 + wm * 64 + mi * 16 + quad * 4 + r;
        int gj = j0 + wn * 32 + ni * 16 + l16;
        Sb[(size_t)gi * 1024 + gj] = smax[mi][ni][r];
      }
  if (jh >= 2 * ti + 2) {
    __syncthreads();                 // staging buffers dead
    float* tl = (float*)smem;        // [128][65] fp32
#pragma unroll
    for (int mi = 0; mi < 4; ++mi)
#pragma unroll
      for (int ni = 0; ni < 2; ++ni)
#pragma unroll
        for (int r = 0; r < 4; ++r)
          tl[(wm * 64 + mi * 16 + quad * 4 + r) * 65 + (wn * 32 + ni * 16 + l16)] =
              smax[mi][ni][r];
    __syncthreads();
#pragma unroll 1
    for (int k = 0; k < 32; ++k) {
      int flat = k * 256 + t;        // 0..8191
      int rm = flat >> 7, cm = flat & 127;   // rm: mirror row 0..63, cm: col 0..127
      Sb[(size_t)(j0 + rm) * 1024 + (i0 + cm)] = tl[cm * 65 + rm];
    }
  }
}

// ---- K3: allennlp masked softmax per row -> alpha fp16 ----
// 8192 blocks x 256 thr; thread t owns elements [4t, 4t+4): float4 S read,
// int4 mask read, half4 alpha write (4x fewer memory instructions).

__global__ __launch_bounds__(256) void softmax_kernel(const float* __restrict__ S,
                                                      const int* __restrict__ xmask,
                                                      _Float16* __restrict__ alpha) {
  __shared__ float red[16];
  int row = blockIdx.x;               // 0..8191
  int b = row >> 10, l = row & 1023;
  const float* sr = S + (size_t)row * 1024;
  const int* mr = xmask + b * 1024;
  int t = threadIdx.x, lane = t & 63, wid = t >> 6;
  int rm = mr[l];
  float4 sv = *(const float4*)(sr + t * 4);
  int4 mv = *(const int4*)(mr + t * 4);
  float v[4], mm[4];
  float vmax = 0.0f;
#pragma unroll
  for (int u = 0; u < 4; ++u) {
    int j = t * 4 + u;
    int mu = ((const int*)&mv)[u];
    int m = (rm && mu && (j != l)) ? 1 : 0;
    mm[u] = (float)m;
    v[u] = m ? ((const float*)&sv)[u] : 0.0f;
    vmax = fmaxf(vmax, v[u]);
  }
  for (int off = 32; off; off >>= 1) vmax = fmaxf(vmax, __shfl_down(vmax, off));
  if (lane == 0) red[wid] = vmax;
  __syncthreads();
  if (t == 0) red[8] = fmaxf(fmaxf(red[0], red[1]), fmaxf(red[2], red[3]));
  __syncthreads();
  vmax = red[8];
  float e[4], E = 0.0f, E2 = 0.0f;
#pragma unroll
  for (int u = 0; u < 4; ++u) {
    e[u] = expf(v[u] - vmax);
    E += e[u];
    E2 += e[u] * mm[u];
  }
  for (int off = 32; off; off >>= 1) {
    E += __shfl_down(E, off);
    E2 += __shfl_down(E2, off);
  }
  if (lane == 0) { red[wid] = E; red[4 + wid] = E2; }
  __syncthreads();
  if (t == 0) {
    red[9] = red[0] + red[1] + red[2] + red[3];
    red[10] = red[4] + red[5] + red[6] + red[7];
  }
  __syncthreads();
  E = red[9]; E2 = red[10];
  float inv = 1.0f / (E2 + 1e-13f * E);
  half4v hv;
#pragma unroll
  for (int u = 0; u < 4; ++u) hv[u] = (_Float16)(e[u] * mm[u] * inv);
  *(half4v*)(alpha + (size_t)row * 1024 + t * 4) = hv;
}

// ---- K4: enc[b] = alpha[b] @ x[b]  (xT (B,H,L) as B-operand) ----
// 512 blocks x 256 thr: 64-row i-tiles x 4 n-tiles x 8 b; b = id & 7 XCD pin.

__global__ __launch_bounds__(256) void attn_kernel(const _Float16* __restrict__ alpha,
                                                   const _Float16* __restrict__ xT,
                                                   _Float16* __restrict__ enc) {
  __shared__ __align__(16) _Float16 ldsA[2][64 * 64];
  __shared__ __align__(16) _Float16 ldsB[2][128 * 64];
  int id = blockIdx.x;
  int b = id & 7;
  int r2 = id >> 3;                 // 0..63
  int i0 = (r2 >> 2) * 64;
  int n0 = (r2 & 3) * 128;
  const _Float16* A = alpha + (size_t)b * 1024 * 1024;
  const _Float16* Bm = xT + (size_t)b * 512 * 1024;
  int t = threadIdx.x, lane = t & 63, wn = t >> 6;   // wave grid 1x4
  int quad = lane >> 4, l16 = lane & 15;
  const _Float16* gpA[2]; const _Float16* gpB[4];
  init_ptrs<2, 256>(A, i0, 1024, gpA);
  init_ptrs<4, 256>(Bm, n0, 1024, gpB);
  floatx4 acc[4][2];
  ZERO_ACC42(acc);
  stage<2, 256>(gpA, ldsA[0]); bump<2>(gpA, 64);
  stage<4, 256>(gpB, ldsB[0]); bump<4>(gpB, 64);
#pragma unroll 1
  for (int kt = 0; kt < 16; ++kt) {
    __syncthreads();
    if (kt < 15) {
      stage<2, 256>(gpA, ldsA[(kt + 1) & 1]); bump<2>(gpA, 64);
      stage<4, 256>(gpB, ldsB[(kt + 1) & 1]); bump<4>(gpB, 64);
    }
    const _Float16* la = ldsA[kt & 1];
    const _Float16* lb = ldsB[kt & 1];
#pragma unroll
    for (int kf = 0; kf < 2; ++kf) {
      half8 af[4], bf[2];
#pragma unroll
      for (int i = 0; i < 4; ++i) af[i] = frag_ld(la, i * 16 + l16, kf * 4 + quad);
#pragma unroll
      for (int i = 0; i < 2; ++i) bf[i] = frag_ld(lb, wn * 32 + i * 16 + l16, kf * 4 + quad);
#pragma unroll
      for (int mi = 0; mi < 4; ++mi)
#pragma unroll
        for (int ni = 0; ni < 2; ++ni)
          acc[mi][ni] = __builtin_amdgcn_mfma_f32_16x16x32_f16(af[mi], bf[ni], acc[mi][ni], 0, 0, 0);
    }
  }
  _Float16* eb = enc + (size_t)b * 1024 * 512;
#pragma unroll
  for (int mi = 0; mi < 4; ++mi)
#pragma unroll
    for (int ni = 0; ni < 2; ++ni)
#pragma unroll
      for (int r = 0; r < 4; ++r) {
        int gr = i0 + mi * 16 + quad * 4 + r;
        int gc = n0 + wn * 32 + ni * 16 + l16;
        eb[(size_t)gr * 512 + gc] = (_Float16)acc[mi][ni][r];
      }
}

// ---- K5: gate = sigmoid([x|enc] @ W_gate + b_gate); out = gate*[x16|enc] ----
// 256 thr, 2x2 waves, dbuf BK=64, grid (64,8), 2 blk/CU.

__global__ __launch_bounds__(256) void gate_kernel(const _Float16* __restrict__ x16,
                                                   const _Float16* __restrict__ enc,
                                                   const _Float16* __restrict__ WgT,
                                                   const float* __restrict__ bg,
                                                   float* __restrict__ out) {
  __shared__ __align__(16) _Float16 ldsA[2][128 * 64];
  __shared__ __align__(16) _Float16 ldsB[2][128 * 64];
  int i0 = blockIdx.x * 128, n0 = blockIdx.y * 128;
  int t = threadIdx.x, lane = t & 63, w = t >> 6;
  int wm = w >> 1, wn = w & 1, quad = lane >> 4, l16 = lane & 15;
  const _Float16* gpA[4]; const _Float16* gpA2[4]; const _Float16* gpB[4];
  init_ptrs<4, 256>(x16, i0, 512, gpA);
  init_ptrs<4, 256>(enc, i0, 512, gpA2);
  init_ptrs<4, 256>(WgT, n0, 1024, gpB);
  floatx4 acc[4][4];
  ZERO_ACC44(acc);
  stage<4, 256>(gpA, ldsA[0]); bump<4>(gpA, 64);
  stage<4, 256>(gpB, ldsB[0]); bump<4>(gpB, 64);
#pragma unroll 1
  for (int kt = 0; kt < 16; ++kt) {
    __syncthreads();
    if (kt < 15) {
      if (kt < 7) { stage<4, 256>(gpA,  ldsA[(kt + 1) & 1]); bump<4>(gpA, 64); }
      else        { stage<4, 256>(gpA2, ldsA[(kt + 1) & 1]); bump<4>(gpA2, 64); }
      stage<4, 256>(gpB, ldsB[(kt + 1) & 1]); bump<4>(gpB, 64);
    }
    mfma_tile44(ldsA[kt & 1], ldsB[kt & 1], acc, wm, wn, l16, quad);
  }
#pragma unroll
  for (int mi = 0; mi < 4; ++mi)
#pragma unroll
    for (int ni = 0; ni < 4; ++ni)
#pragma unroll
      for (int r = 0; r < 4; ++r) {
        int gr = i0 + wm * 64 + mi * 16 + quad * 4 + r;  // 0..8191
        int gc = n0 + wn * 64 + ni * 16 + l16;           // 0..1023
        float c = acc[mi][ni][r] + bg[gc];
        float g = 1.0f / (1.0f + expf(-c));
        float jv = (gc < 512) ? (float)x16[(size_t)gr * 512 + gc]
                              : (float)enc[(size_t)gr * 512 + (gc - 512)];
        out[(size_t)gr * 1024 + gc] = g * jv;
      }
}

// ---- launch ----

extern "C" void kernel_launch(void* const* d_in, const int* in_sizes, int n_in,
                              void* d_out, int out_size, void* d_ws, size_t ws_size,
                              hipStream_t stream) {
  const float* x  = (const float*)d_in[0];   // (8,1024,512)
  const int* xm   = (const int*)d_in[1];     // (8,1024)
  const float* Wp = (const float*)d_in[2];   // (512,2048)
  const float* bp = (const float*)d_in[3];   // (2048)
  const float* Wg = (const float*)d_in[4];   // (1024,1024)
  const float* bg = (const float*)d_in[5];   // (1024)
  float* out = (float*)d_out;

  char* ws = (char*)d_ws;
  const size_t MB = 1024 * 1024;
  _Float16* x16 = (_Float16*)(ws);            // 8 MB  (8192,512)
  _Float16* xT  = (_Float16*)(ws + 8 * MB);   // 8 MB  (8,512,1024)
  _Float16* WpT = (_Float16*)(ws + 16 * MB);  // 2 MB  (2048,512) row-permuted
  _Float16* WgT = (_Float16*)(ws + 18 * MB);  // 2 MB  (1024,1024)
  _Float16* y_t = (_Float16*)(ws + 20 * MB);  // 32 MB (8,4,1024,512)
  float*    S   = (float*)(ws + 52 * MB);     // 32 MB (8,1024,1024)  [end: 84 MB]
  // y_t is dead after score_kernel: alias alpha/enc onto it
  _Float16* alpha = (_Float16*)(ws + 20 * MB); // 16 MB (8,1024,1024)
  _Float16* enc   = (_Float16*)(ws + 36 * MB); // 8 MB  (8,1024,512)

  prep_kernel<<<6144, 256, 0, stream>>>(x, x16, xT, Wp, WpT, Wg, WgT);

  proj_kernel<<<dim3(64, 16), 256, 0, stream>>>(x16, WpT, bp, y_t);
  score_kernel<<<576, 256, 0, stream>>>(y_t, S);
  softmax_kernel<<<8192, 256, 0, stream>>>(S, xm, alpha);
  attn_kernel<<<512, 256, 0, stream>>>(alpha, xT, enc);
  gate_kernel<<<dim3(64, 8), 256, 0, stream>>>(x16, enc, WgT, bg, out);
}

// Round 12
// 191.952 us; speedup vs baseline: 1.0779x; 1.0187x over previous
//
#include <hip/hip_runtime.h>

// Problem constants: B=8, L=1024, H=512, F=4
// out = gate * [x | alpha @ x],  gate = sigmoid([x|enc] @ W_gate)
// alpha = masked_softmax(max_f(Y_f Y_f^T)),  Y = relu(x @ W_proj)
//
// Round 24 = R23 (195.6us, session best) + __expf in softmax/gate
// (skips libm range-reduction; softmax is issue-limited; ~2ULP fp32 error
// vanishes in fp16 output rounding). Session ledger: R13 rebalance +3us;
// R14 XCD pin neutral; R15-R18 deep pipelines slower; R20 fusion slower;
// R21 vectorized softmax +2us; R22 fp16-S fails accuracy; R23 revert =
// best. Structure: 2-phase dbuf BK=64 GEMMs at 2 blk/CU, upper-tri score
// with LDS-transpose mirror, vectorized 8192-block softmax, merged prep,
// XCD-pinned score/attn.

typedef _Float16 half8 __attribute__((ext_vector_type(8)));
typedef _Float16 half4v __attribute__((ext_vector_type(4)));
typedef float floatx4 __attribute__((ext_vector_type(4)));

typedef const __attribute__((address_space(1))) void* gas_ptr;
typedef __attribute__((address_space(3))) void* las_ptr;

// ---- staging machinery: BK=64 rows (64 fp16/row), XOR-swizzle by row&7 ----
// Chunk c covers row=c>>3, group kg=c&7, global col (kg^(row&7))*8; LDS dst =
// c*16 B (wave-uniform base + lane*16 contract of global_load_lds). Row
// stride 128 B = 32 banks -> rows never alias; swizzle makes frag reads clean.

template<int NCH, int NT>
__device__ __forceinline__ void init_ptrs(const _Float16* src, int row0, int ld,
                                          const _Float16* gp[NCH]) {
  int t = threadIdx.x;
#pragma unroll
  for (int p = 0; p < NCH; ++p) {
    int c = p * NT + t;
    int row = c >> 3;
    int kg = c & 7;
    int gk = (kg ^ (row & 7)) << 3;
    gp[p] = src + (size_t)(row0 + row) * ld + gk;
  }
}

template<int NCH, int NT>
__device__ __forceinline__ void stage(const _Float16* const gp[NCH], _Float16* ldsbuf) {
  int t = threadIdx.x;
#pragma unroll
  for (int p = 0; p < NCH; ++p)
    __builtin_amdgcn_global_load_lds((gas_ptr)gp[p],
                                     (las_ptr)(ldsbuf + t * 8 + p * NT * 8), 16, 0, 0);
}

template<int NCH>
__device__ __forceinline__ void bump(const _Float16* gp[NCH], int d) {
#pragma unroll
  for (int p = 0; p < NCH; ++p) gp[p] += d;
}

__device__ __forceinline__ half8 frag_ld(const _Float16* lds, int row, int g) {
  return *(const half8*)(lds + row * 64 + ((g ^ (row & 7)) << 3));
}

// 4-wave (2x2) block: wave tile 64x64, per-lane acc 4x4
__device__ __forceinline__ void mfma_tile44(const _Float16* lds_a, const _Float16* lds_b,
                                            floatx4 acc[4][4], int wm, int wn,
                                            int l16, int quad) {
#pragma unroll
  for (int kf = 0; kf < 2; ++kf) {
    half8 af[4], bf[4];
#pragma unroll
    for (int i = 0; i < 4; ++i) af[i] = frag_ld(lds_a, wm * 64 + i * 16 + l16, kf * 4 + quad);
#pragma unroll
    for (int i = 0; i < 4; ++i) bf[i] = frag_ld(lds_b, wn * 64 + i * 16 + l16, kf * 4 + quad);
#pragma unroll
    for (int mi = 0; mi < 4; ++mi)
#pragma unroll
      for (int ni = 0; ni < 4; ++ni)
        acc[mi][ni] = __builtin_amdgcn_mfma_f32_16x16x32_f16(af[mi], bf[ni], acc[mi][ni], 0, 0, 0);
  }
}

#define ZERO_ACC44(acc)                                 \
  _Pragma("unroll") for (int mi = 0; mi < 4; ++mi)      \
  _Pragma("unroll") for (int ni = 0; ni < 4; ++ni)      \
  _Pragma("unroll") for (int r = 0; r < 4; ++r) acc[mi][ni][r] = 0.0f;

// wave tile 64x32, per-lane acc 4x2 (score/attn)
__device__ __forceinline__ void mfma_tile42(const _Float16* la, const _Float16* lb,
                                            floatx4 acc[4][2], int wm, int wn,
                                            int l16, int quad) {
#pragma unroll
  for (int kf = 0; kf < 2; ++kf) {
    half8 af[4], bf[2];
#pragma unroll
    for (int i = 0; i < 4; ++i) af[i] = frag_ld(la, wm * 64 + i * 16 + l16, kf * 4 + quad);
#pragma unroll
    for (int i = 0; i < 2; ++i) bf[i] = frag_ld(lb, wn * 32 + i * 16 + l16, kf * 4 + quad);
#pragma unroll
    for (int mi = 0; mi < 4; ++mi)
#pragma unroll
      for (int ni = 0; ni < 2; ++ni)
        acc[mi][ni] = __builtin_amdgcn_mfma_f32_16x16x32_f16(af[mi], bf[ni], acc[mi][ni], 0, 0, 0);
  }
}

#define ZERO_ACC42(acc)                                 \
  _Pragma("unroll") for (int mi = 0; mi < 4; ++mi)      \
  _Pragma("unroll") for (int ni = 0; ni < 2; ++ni)      \
  _Pragma("unroll") for (int r = 0; r < 4; ++r) acc[mi][ni][r] = 0.0f;

// ---- merged pre-pass: ids [0,4096) = x_prep, [4096,6144) = w_prep ----

__global__ __launch_bounds__(256) void prep_kernel(const float* __restrict__ xin,
                                                   _Float16* __restrict__ x16,
                                                   _Float16* __restrict__ xT,
                                                   const float* __restrict__ Wp,
                                                   _Float16* __restrict__ WpT,
                                                   const float* __restrict__ Wg,
                                                   _Float16* __restrict__ WgT) {
  __shared__ float tile[32][33];
  int id = blockIdx.x;
  int tx = threadIdx.x & 31, ty = threadIdx.x >> 5;  // 32 x 8
  if (id < 4096) {
    const int R = 1024, C = 512;
    int b = id & 7, rest = id >> 3;
    int c0 = (rest & 15) * 32, r0 = (rest >> 4) * 32;
    size_t boff = (size_t)b * R * C;
    const float* in = xin + boff;
    _Float16* o16 = x16 + boff;
    _Float16* oT = xT + boff;
#pragma unroll
    for (int i = 0; i < 32; i += 8) {
      float v = in[(size_t)(r0 + ty + i) * C + c0 + tx];
      tile[ty + i][tx] = v;
      o16[(size_t)(r0 + ty + i) * C + c0 + tx] = (_Float16)v;
    }
    __syncthreads();
#pragma unroll
    for (int i = 0; i < 32; i += 8)
      oT[(size_t)(c0 + ty + i) * R + r0 + tx] = (_Float16)tile[tx][ty + i];
  } else {
    // z=0: Wp (512,2048) -> WpT' (2048,512) row-permuted (col k=h*4+f ->
    // row f*512+h, so proj's output col n = f*512+h). z=1: Wg -> WgT.
    int w = id - 4096;
    int bx = w & 63, by = (w >> 6) & 15, bz = w >> 10;
    const float* in; _Float16* out; int R, C, c0, r0;
    if (bz == 0) {
      in = Wp; out = WpT; R = 512; C = 2048;
      c0 = bx * 32; r0 = by * 32;
    } else {
      in = Wg; out = WgT; R = 1024; C = 1024;
      c0 = (bx & 31) * 32; r0 = (by * 2 + (bx >> 5)) * 32;
    }
#pragma unroll
    for (int i = 0; i < 32; i += 8)
      tile[ty + i][tx] = in[(size_t)(r0 + ty + i) * C + c0 + tx];
    __syncthreads();
#pragma unroll
    for (int i = 0; i < 32; i += 8) {
      int rr = c0 + ty + i;            // original column index of `in`
      int prow = (bz == 0) ? ((rr & 3) * 512 + (rr >> 2)) : rr;
      out[(size_t)prow * R + r0 + tx] = (_Float16)tile[tx][ty + i];
    }
  }
}

// ---- K1: y = relu(x @ W_proj + b_proj) -> y_t (B,F,L,H) fp16 ----
// 256 thr, 2x2 waves, 128x128 tile, dbuf BK=64, grid (64,16), 2 blk/CU.

__global__ __launch_bounds__(256) void proj_kernel(const _Float16* __restrict__ x16,
                                                   const _Float16* __restrict__ WpT,
                                                   const float* __restrict__ bp,
                                                   _Float16* __restrict__ y_t) {
  __shared__ __align__(16) _Float16 ldsA[2][128 * 64];
  __shared__ __align__(16) _Float16 ldsB[2][128 * 64];
  int i0 = blockIdx.x * 128, n0 = blockIdx.y * 128;
  int t = threadIdx.x, lane = t & 63, w = t >> 6;
  int wm = w >> 1, wn = w & 1, quad = lane >> 4, l16 = lane & 15;
  const _Float16* gpA[4]; const _Float16* gpB[4];
  init_ptrs<4, 256>(x16, i0, 512, gpA);
  init_ptrs<4, 256>(WpT, n0, 512, gpB);
  floatx4 acc[4][4];
  ZERO_ACC44(acc);
  stage<4, 256>(gpA, ldsA[0]); bump<4>(gpA, 64);
  stage<4, 256>(gpB, ldsB[0]); bump<4>(gpB, 64);
#pragma unroll 1
  for (int kt = 0; kt < 8; ++kt) {
    __syncthreads();
    if (kt < 7) {
      stage<4, 256>(gpA, ldsA[(kt + 1) & 1]); bump<4>(gpA, 64);
      stage<4, 256>(gpB, ldsB[(kt + 1) & 1]); bump<4>(gpB, 64);
    }
    mfma_tile44(ldsA[kt & 1], ldsB[kt & 1], acc, wm, wn, l16, quad);
  }
#pragma unroll
  for (int mi = 0; mi < 4; ++mi)
#pragma unroll
    for (int ni = 0; ni < 4; ++ni)
#pragma unroll
      for (int r = 0; r < 4; ++r) {
        int gr = i0 + wm * 64 + mi * 16 + quad * 4 + r;   // 0..8191
        int gc = n0 + wn * 64 + ni * 16 + l16;            // permuted col f*512+h
        int f = gc >> 9, h = gc & 511;
        float c = fmaxf(acc[mi][ni][r] + bp[h * 4 + f], 0.0f);
        int b = gr >> 10, l = gr & 1023;
        y_t[(((size_t)(b * 4 + f)) * 1024 + l) * 512 + h] = (_Float16)c;
      }
}

// ---- K2: S[b,i,j] = max_f sum_h Y_f[i,h] Y_f[j,h]; S symmetric ----
// 576 blocks (8 b x 72 upper-tri 128x64 tiles) x 256 thr; b = id & 7 XCD pin.
// 48KB LDS -> 3 blocks/CU. Diagonal covered by jh=2ti/2ti+1 direct;
// jh>=2ti+2 mirrored via [128][65] fp32 LDS transpose (conflict-free).

__global__ __launch_bounds__(256, 3) void score_kernel(const _Float16* __restrict__ y_t,
                                                       float* __restrict__ S) {
  __shared__ __align__(16) char smem[49152];
  _Float16* LA0 = (_Float16*)smem;              // 16 KB (128x64)
  _Float16* LA1 = (_Float16*)(smem + 16384);    // 16 KB
  _Float16* LB0 = (_Float16*)(smem + 32768);    // 8 KB (64x64)
  _Float16* LB1 = (_Float16*)(smem + 40960);    // 8 KB
  int id = blockIdx.x;
  int b = id & 7;
  int tt = id >> 3;            // 0..71 upper-tri half-tile index
  int ti = 0;
  while (tt >= 16 - 2 * ti) { tt -= 16 - 2 * ti; ++ti; }
  int jh = 2 * ti + tt;        // 2*ti .. 15
  int i0 = ti * 128, j0 = jh * 64;
  int t = threadIdx.x, lane = t & 63, w = t >> 6;
  int wm = w >> 1, wn = w & 1, quad = lane >> 4, l16 = lane & 15;
  const int PLANE = 1024 * 512;
  const _Float16* base = y_t + (size_t)b * 4 * PLANE;
  const _Float16* gpA[4]; const _Float16* gpB[2];
  init_ptrs<4, 256>(base, i0, 512, gpA);
  init_ptrs<2, 256>(base, j0, 512, gpB);
  floatx4 acc[4][2], smax[4][2];
  ZERO_ACC42(acc);
  stage<4, 256>(gpA, LA0); bump<4>(gpA, 64);
  stage<2, 256>(gpB, LB0); bump<2>(gpB, 64);
#pragma unroll 1
  for (int f = 0; f < 4; ++f) {
#pragma unroll 1
    for (int kt = 0; kt < 8; ++kt) {
      __syncthreads();
      if (f * 8 + kt < 31) {
        if (kt == 7) { bump<4>(gpA, PLANE - 512); bump<2>(gpB, PLANE - 512); }
        stage<4, 256>(gpA, ((kt + 1) & 1) ? LA1 : LA0); bump<4>(gpA, 64);
        stage<2, 256>(gpB, ((kt + 1) & 1) ? LB1 : LB0); bump<2>(gpB, 64);
      }
      mfma_tile42((kt & 1) ? LA1 : LA0, (kt & 1) ? LB1 : LB0, acc, wm, wn, l16, quad);
    }
    if (f == 0) {
#pragma unroll
      for (int mi = 0; mi < 4; ++mi)
#pragma unroll
        for (int ni = 0; ni < 2; ++ni) smax[mi][ni] = acc[mi][ni];
    } else {
#pragma unroll
      for (int mi = 0; mi < 4; ++mi)
#pragma unroll
        for (int ni = 0; ni < 2; ++ni)
#pragma unroll
          for (int r = 0; r < 4; ++r)
            smax[mi][ni][r] = fmaxf(smax[mi][ni][r], acc[mi][ni][r]);
    }
    ZERO_ACC42(acc);
  }
  float* Sb = S + (size_t)b * 1024 * 1024;
#pragma unroll
  for (int mi = 0; mi < 4; ++mi)
#pragma unroll
    for (int ni = 0; ni < 2; ++ni)
#pragma unroll
      for (int r = 0; r < 4; ++r) {
        int gi = i0 + wm * 64 + mi * 16 + quad * 4 + r;
        int gj = j0 + wn * 32 + ni * 16 + l16;
        Sb[(size_t)gi * 1024 + gj] = smax[mi][ni][r];
      }
  if (jh >= 2 * ti + 2) {
    __syncthreads();                 // staging buffers dead
    float* tl = (float*)smem;        // [128][65] fp32
#pragma unroll
    for (int mi = 0; mi < 4; ++mi)
#pragma unroll
      for (int ni = 0; ni < 2; ++ni)
#pragma unroll
        for (int r = 0; r < 4; ++r)
          tl[(wm * 64 + mi * 16 + quad * 4 + r) * 65 + (wn * 32 + ni * 16 + l16)] =
              smax[mi][ni][r];
    __syncthreads();
#pragma unroll 1
    for (int k = 0; k < 32; ++k) {
      int flat = k * 256 + t;        // 0..8191
      int rm = flat >> 7, cm = flat & 127;   // rm: mirror row 0..63, cm: col 0..127
      Sb[(size_t)(j0 + rm) * 1024 + (i0 + cm)] = tl[cm * 65 + rm];
    }
  }
}

// ---- K3: allennlp masked softmax per row -> alpha fp16 ----
// 8192 blocks x 256 thr; thread t owns elements [4t, 4t+4): float4 S read,
// int4 mask read, half4 alpha write. __expf (2ULP) vanishes in fp16 round.

__global__ __launch_bounds__(256) void softmax_kernel(const float* __restrict__ S,
                                                      const int* __restrict__ xmask,
                                                      _Float16* __restrict__ alpha) {
  __shared__ float red[16];
  int row = blockIdx.x;               // 0..8191
  int b = row >> 10, l = row & 1023;
  const float* sr = S + (size_t)row * 1024;
  const int* mr = xmask + b * 1024;
  int t = threadIdx.x, lane = t & 63, wid = t >> 6;
  int rm = mr[l];
  float4 sv = *(const float4*)(sr + t * 4);
  int4 mv = *(const int4*)(mr + t * 4);
  float v[4], mm[4];
  float vmax = 0.0f;
#pragma unroll
  for (int u = 0; u < 4; ++u) {
    int j = t * 4 + u;
    int mu = ((const int*)&mv)[u];
    int m = (rm && mu && (j != l)) ? 1 : 0;
    mm[u] = (float)m;
    v[u] = m ? ((const float*)&sv)[u] : 0.0f;
    vmax = fmaxf(vmax, v[u]);
  }
  for (int off = 32; off; off >>= 1) vmax = fmaxf(vmax, __shfl_down(vmax, off));
  if (lane == 0) red[wid] = vmax;
  __syncthreads();
  if (t == 0) red[8] = fmaxf(fmaxf(red[0], red[1]), fmaxf(red[2], red[3]));
  __syncthreads();
  vmax = red[8];
  float e[4], E = 0.0f, E2 = 0.0f;
#pragma unroll
  for (int u = 0; u < 4; ++u) {
    e[u] = __expf(v[u] - vmax);
    E += e[u];
    E2 += e[u] * mm[u];
  }
  for (int off = 32; off; off >>= 1) {
    E += __shfl_down(E, off);
    E2 += __shfl_down(E2, off);
  }
  if (lane == 0) { red[wid] = E; red[4 + wid] = E2; }
  __syncthreads();
  if (t == 0) {
    red[9] = red[0] + red[1] + red[2] + red[3];
    red[10] = red[4] + red[5] + red[6] + red[7];
  }
  __syncthreads();
  E = red[9]; E2 = red[10];
  float inv = 1.0f / (E2 + 1e-13f * E);
  half4v hv;
#pragma unroll
  for (int u = 0; u < 4; ++u) hv[u] = (_Float16)(e[u] * mm[u] * inv);
  *(half4v*)(alpha + (size_t)row * 1024 + t * 4) = hv;
}

// ---- K4: enc[b] = alpha[b] @ x[b]  (xT (B,H,L) as B-operand) ----
// 512 blocks x 256 thr: 64-row i-tiles x 4 n-tiles x 8 b; b = id & 7 XCD pin.

__global__ __launch_bounds__(256) void attn_kernel(const _Float16* __restrict__ alpha,
                                                   const _Float16* __restrict__ xT,
                                                   _Float16* __restrict__ enc) {
  __shared__ __align__(16) _Float16 ldsA[2][64 * 64];
  __shared__ __align__(16) _Float16 ldsB[2][128 * 64];
  int id = blockIdx.x;
  int b = id & 7;
  int r2 = id >> 3;                 // 0..63
  int i0 = (r2 >> 2) * 64;
  int n0 = (r2 & 3) * 128;
  const _Float16* A = alpha + (size_t)b * 1024 * 1024;
  const _Float16* Bm = xT + (size_t)b * 512 * 1024;
  int t = threadIdx.x, lane = t & 63, wn = t >> 6;   // wave grid 1x4
  int quad = lane >> 4, l16 = lane & 15;
  const _Float16* gpA[2]; const _Float16* gpB[4];
  init_ptrs<2, 256>(A, i0, 1024, gpA);
  init_ptrs<4, 256>(Bm, n0, 1024, gpB);
  floatx4 acc[4][2];
  ZERO_ACC42(acc);
  stage<2, 256>(gpA, ldsA[0]); bump<2>(gpA, 64);
  stage<4, 256>(gpB, ldsB[0]); bump<4>(gpB, 64);
#pragma unroll 1
  for (int kt = 0; kt < 16; ++kt) {
    __syncthreads();
    if (kt < 15) {
      stage<2, 256>(gpA, ldsA[(kt + 1) & 1]); bump<2>(gpA, 64);
      stage<4, 256>(gpB, ldsB[(kt + 1) & 1]); bump<4>(gpB, 64);
    }
    const _Float16* la = ldsA[kt & 1];
    const _Float16* lb = ldsB[kt & 1];
#pragma unroll
    for (int kf = 0; kf < 2; ++kf) {
      half8 af[4], bf[2];
#pragma unroll
      for (int i = 0; i < 4; ++i) af[i] = frag_ld(la, i * 16 + l16, kf * 4 + quad);
#pragma unroll
      for (int i = 0; i < 2; ++i) bf[i] = frag_ld(lb, wn * 32 + i * 16 + l16, kf * 4 + quad);
#pragma unroll
      for (int mi = 0; mi < 4; ++mi)
#pragma unroll
        for (int ni = 0; ni < 2; ++ni)
          acc[mi][ni] = __builtin_amdgcn_mfma_f32_16x16x32_f16(af[mi], bf[ni], acc[mi][ni], 0, 0, 0);
    }
  }
  _Float16* eb = enc + (size_t)b * 1024 * 512;
#pragma unroll
  for (int mi = 0; mi < 4; ++mi)
#pragma unroll
    for (int ni = 0; ni < 2; ++ni)
#pragma unroll
      for (int r = 0; r < 4; ++r) {
        int gr = i0 + mi * 16 + quad * 4 + r;
        int gc = n0 + wn * 32 + ni * 16 + l16;
        eb[(size_t)gr * 512 + gc] = (_Float16)acc[mi][ni][r];
      }
}

// ---- K5: gate = sigmoid([x|enc] @ W_gate + b_gate); out = gate*[x16|enc] ----
// 256 thr, 2x2 waves, dbuf BK=64, grid (64,8), 2 blk/CU.

__global__ __launch_bounds__(256) void gate_kernel(const _Float16* __restrict__ x16,
                                                   const _Float16* __restrict__ enc,
                                                   const _Float16* __restrict__ WgT,
                                                   const float* __restrict__ bg,
                                                   float* __restrict__ out) {
  __shared__ __align__(16) _Float16 ldsA[2][128 * 64];
  __shared__ __align__(16) _Float16 ldsB[2][128 * 64];
  int i0 = blockIdx.x * 128, n0 = blockIdx.y * 128;
  int t = threadIdx.x, lane = t & 63, w = t >> 6;
  int wm = w >> 1, wn = w & 1, quad = lane >> 4, l16 = lane & 15;
  const _Float16* gpA[4]; const _Float16* gpA2[4]; const _Float16* gpB[4];
  init_ptrs<4, 256>(x16, i0, 512, gpA);
  init_ptrs<4, 256>(enc, i0, 512, gpA2);
  init_ptrs<4, 256>(WgT, n0, 1024, gpB);
  floatx4 acc[4][4];
  ZERO_ACC44(acc);
  stage<4, 256>(gpA, ldsA[0]); bump<4>(gpA, 64);
  stage<4, 256>(gpB, ldsB[0]); bump<4>(gpB, 64);
#pragma unroll 1
  for (int kt = 0; kt < 16; ++kt) {
    __syncthreads();
    if (kt < 15) {
      if (kt < 7) { stage<4, 256>(gpA,  ldsA[(kt + 1) & 1]); bump<4>(gpA, 64); }
      else        { stage<4, 256>(gpA2, ldsA[(kt + 1) & 1]); bump<4>(gpA2, 64); }
      stage<4, 256>(gpB, ldsB[(kt + 1) & 1]); bump<4>(gpB, 64);
    }
    mfma_tile44(ldsA[kt & 1], ldsB[kt & 1], acc, wm, wn, l16, quad);
  }
#pragma unroll
  for (int mi = 0; mi < 4; ++mi)
#pragma unroll
    for (int ni = 0; ni < 4; ++ni)
#pragma unroll
      for (int r = 0; r < 4; ++r) {
        int gr = i0 + wm * 64 + mi * 16 + quad * 4 + r;  // 0..8191
        int gc = n0 + wn * 64 + ni * 16 + l16;           // 0..1023
        float c = acc[mi][ni][r] + bg[gc];
        float g = 1.0f / (1.0f + __expf(-c));
        float jv = (gc < 512) ? (float)x16[(size_t)gr * 512 + gc]
                              : (float)enc[(size_t)gr * 512 + (gc - 512)];
        out[(size_t)gr * 1024 + gc] = g * jv;
      }
}

// ---- launch ----

extern "C" void kernel_launch(void* const* d_in, const int* in_sizes, int n_in,
                              void* d_out, int out_size, void* d_ws, size_t ws_size,
                              hipStream_t stream) {
  const float* x  = (const float*)d_in[0];   // (8,1024,512)
  const int* xm   = (const int*)d_in[1];     // (8,1024)
  const float* Wp = (const float*)d_in[2];   // (512,2048)
  const float* bp = (const float*)d_in[3];   // (2048)
  const float* Wg = (const float*)d_in[4];   // (1024,1024)
  const float* bg = (const float*)d_in[5];   // (1024)
  float* out = (float*)d_out;

  char* ws = (char*)d_ws;
  const size_t MB = 1024 * 1024;
  _Float16* x16 = (_Float16*)(ws);            // 8 MB  (8192,512)
  _Float16* xT  = (_Float16*)(ws + 8 * MB);   // 8 MB  (8,512,1024)
  _Float16* WpT = (_Float16*)(ws + 16 * MB);  // 2 MB  (2048,512) row-permuted
  _Float16* WgT = (_Float16*)(ws + 18 * MB);  // 2 MB  (1024,1024)
  _Float16* y_t = (_Float16*)(ws + 20 * MB);  // 32 MB (8,4,1024,512)
  float*    S   = (float*)(ws + 52 * MB);     // 32 MB (8,1024,1024)  [end: 84 MB]
  // y_t is dead after score_kernel: alias alpha/enc onto it
  _Float16* alpha = (_Float16*)(ws + 20 * MB); // 16 MB (8,1024,1024)
  _Float16* enc   = (_Float16*)(ws + 36 * MB); // 8 MB  (8,1024,512)

  prep_kernel<<<6144, 256, 0, stream>>>(x, x16, xT, Wp, WpT, Wg, WgT);

  proj_kernel<<<dim3(64, 16), 256, 0, stream>>>(x16, WpT, bp, y_t);
  score_kernel<<<576, 256, 0, stream>>>(y_t, S);
  softmax_kernel<<<8192, 256, 0, stream>>>(S, xm, alpha);
  attn_kernel<<<512, 256, 0, stream>>>(alpha, xT, enc);
  gate_kernel<<<dim3(64, 8), 256, 0, stream>>>(x16, enc, WgT, bg, out);
}